// Round 7
// baseline (693.516 us; speedup 1.0000x reference)
//
#include <hip/hip_runtime.h>

typedef unsigned short u16;
typedef unsigned int   u32;
typedef unsigned char  u8;

using bf16x8 = __attribute__((ext_vector_type(8))) short;
using f32x4  = __attribute__((ext_vector_type(4))) float;
using i32x4  = __attribute__((ext_vector_type(4))) int;

#define SEQ    2048
#define DIMC   2048
#define TOK    4096
#define QKV_N  3072
#define GU_N   11008
#define MLP_P  5504
#define MLP_R  5461
#define ATT_SCALE 0.08838834764831845f

__device__ __forceinline__ float bf2f(u16 v){ return __uint_as_float(((u32)v) << 16); }
__device__ __forceinline__ u16 f2bf(float f){
  u32 x = __float_as_uint(f);
  u32 r = (x + 0x7fffu + ((x >> 16) & 1u)) >> 16;
  return (u16)r;
}

__device__ __forceinline__ float waveRedSum(float v){
#pragma unroll
  for (int o = 32; o > 0; o >>= 1) v += __shfl_xor(v, o);
  return v;
}
__device__ __forceinline__ float waveRedMax(float v){
#pragma unroll
  for (int o = 32; o > 0; o >>= 1) v = fmaxf(v, __shfl_xor(v, o));
  return v;
}

// async global->LDS, 16B per lane. LDS dest is wave-uniform base + lane*16.
#define GLD16(gp, lp) __builtin_amdgcn_global_load_lds( \
    (__attribute__((address_space(1))) void*)(gp), \
    (__attribute__((address_space(3))) void*)(lp), 16, 0, 0)

#define FENCE() asm volatile("" ::: "memory")
#define SBAR()  do{ FENCE(); __builtin_amdgcn_s_barrier(); FENCE(); }while(0)
#define VMCNT(n) asm volatile("s_waitcnt vmcnt(" #n ")" ::: "memory")

// ---------------- fused weight abs-sums (7 regions in one dispatch) ----------------
__global__ __launch_bounds__(256) void k_abssum7(
    const float4* __restrict__ w0, const float4* __restrict__ w1,
    const float4* __restrict__ w2, const float4* __restrict__ w3,
    const float4* __restrict__ w4, const float4* __restrict__ w5,
    const float4* __restrict__ w6, float* __restrict__ sc){
  const int rg = blockIdx.y;
  const float4* w = rg==0?w0: rg==1?w1: rg==2?w2: rg==3?w3: rg==4?w4: rg==5?w5: w6;
  const int n4 = (rg==0||rg==3) ? 1048576 : (rg<4 ? 262144 : 2796032);
  float s = 0.f;
  for (int i = blockIdx.x*256 + threadIdx.x; i < n4; i += gridDim.x*256){
    float4 v = w[i];
    s += fabsf(v.x) + fabsf(v.y) + fabsf(v.z) + fabsf(v.w);
  }
  s = waveRedSum(s);
  __shared__ float sm[4];
  int lane = threadIdx.x & 63, wv = threadIdx.x >> 6;
  if (lane == 0) sm[wv] = s;
  __syncthreads();
  if (threadIdx.x == 0) atomicAdd(sc + rg, sm[0]+sm[1]+sm[2]+sm[3]);
}

// sums at sc[0..6] -> deq (=clip(mean,1e-5)) at sc[8..14]
__global__ void k_finalize(float* __restrict__ sc){
  if (threadIdx.x == 0){
    const float counts[7] = {4194304.f, 1048576.f, 1048576.f, 4194304.f,
                             11184128.f, 11184128.f, 11184128.f};
    for (int i = 0; i < 7; i++) sc[8+i] = fmaxf(sc[i]/counts[i], 1e-5f);
  }
}

// ---------------- fused ternary weight quant (6 regions) -> packed i8 ----------------
// Regions 4 (gate) and 5 (up) are written INTERLEAVED into Wgu:
//   gate row j -> Wgu row 32*(j>>4) + (j&15)
//   up   row j -> Wgu row 32*(j>>4) + 16 + (j&15)
__global__ __launch_bounds__(256) void k_wquant6(
    const float4* __restrict__ w0, const float4* __restrict__ w1,
    const float4* __restrict__ w2, const float4* __restrict__ w3,
    const float4* __restrict__ w4, const float4* __restrict__ w5,
    u32* __restrict__ d0, u32* __restrict__ d1, u32* __restrict__ d2,
    u32* __restrict__ d3, u32* __restrict__ dgu,
    const float* __restrict__ sc){
  const int rg = blockIdx.y;
  const float4* src = rg==0?w0: rg==1?w1: rg==2?w2: rg==3?w3: rg==4?w4: w5;
  const int n4 = (rg==0||rg==3) ? 1048576 : (rg<4 ? 262144 : 2796032);
  float ws = 1.0f / sc[8+rg];
  for (int i = blockIdx.x*256 + threadIdx.x; i < n4; i += gridDim.x*256){
    float4 v = src[i];
    int c0 = (int)fminf(fmaxf(rintf(v.x*ws), -1.f), 1.f);
    int c1 = (int)fminf(fmaxf(rintf(v.y*ws), -1.f), 1.f);
    int c2 = (int)fminf(fmaxf(rintf(v.z*ws), -1.f), 1.f);
    int c3 = (int)fminf(fmaxf(rintf(v.w*ws), -1.f), 1.f);
    u32 pk = (u32)(u8)c0 | ((u32)(u8)c1 << 8) | ((u32)(u8)c2 << 16) | ((u32)(u8)c3 << 24);
    if (rg < 4){
      u32* dst = rg==0?d0: rg==1?d1: rg==2?d2: d3;
      dst[i] = pk;
    } else {
      int row = i >> 9, col = i & 511;            // 512 u32 per 2048-col row
      int rI = 32*(row>>4) + (row&15) + ((rg==5)?16:0);
      dgu[(long)rI*512 + col] = pk;
    }
  }
}

// down_w [2048][5461] fp32 -> [2048][5504] i8 padded with zeros
__global__ __launch_bounds__(256) void k_wquant_down(const float* __restrict__ src,
                                                     u32* __restrict__ dst,
                                                     const float* __restrict__ deqp){
  int i = blockIdx.x*256 + threadIdx.x;
  const int total = 2048*(MLP_P/4);
  if (i >= total) return;
  float ws = 1.0f / deqp[0];
  int r = i / (MLP_P/4);
  int c4 = (i - r*(MLP_P/4))*4;
  u32 o = 0;
#pragma unroll
  for (int e = 0; e < 4; e++){
    int c = c4 + e;
    int t = 0;
    if (c < MLP_R) t = (int)fminf(fmaxf(rintf(src[(long)r*MLP_R + c]*ws), -1.f), 1.f);
    o |= (u32)(u8)t << (8*e);
  }
  dst[i] = o;
}

// ---------------- rmsnorm (optional) + act_quant over 2048 -> i8 ----------------
__global__ __launch_bounds__(256) void k_rmsq(const float* __restrict__ in,
                                              const float* __restrict__ nw,
                                              char* __restrict__ outq,
                                              float* __restrict__ rowdeq, int do_norm){
  const int row = blockIdx.x, tid = threadIdx.x;
  const float* xp = in + (long)row * DIMC + tid*8;
  float v[8];
  float4 a0 = *(const float4*)xp;
  float4 a1 = *(const float4*)(xp + 4);
  v[0]=a0.x; v[1]=a0.y; v[2]=a0.z; v[3]=a0.w;
  v[4]=a1.x; v[5]=a1.y; v[6]=a1.z; v[7]=a1.w;
  float ss = 0.f;
#pragma unroll
  for (int j = 0; j < 8; j++) ss += v[j]*v[j];
  __shared__ float sm[8];
  int lane = tid & 63, wv = tid >> 6;
  ss = waveRedSum(ss);
  if (lane == 0) sm[wv] = ss;
  __syncthreads();
  float h[8];
  float amax = 0.f;
  if (do_norm){
    float tot = sm[0]+sm[1]+sm[2]+sm[3];
    float rms = rsqrtf(tot * (1.0f/DIMC) + 1.1920929e-07f);
    float4 w0 = *(const float4*)(nw + tid*8);
    float4 w1 = *(const float4*)(nw + tid*8 + 4);
    float wr8[8] = {w0.x,w0.y,w0.z,w0.w,w1.x,w1.y,w1.z,w1.w};
#pragma unroll
    for (int j = 0; j < 8; j++){ h[j] = v[j]*rms*wr8[j]; amax = fmaxf(amax, fabsf(h[j])); }
  } else {
#pragma unroll
    for (int j = 0; j < 8; j++){ h[j] = v[j]; amax = fmaxf(amax, fabsf(h[j])); }
  }
  amax = waveRedMax(amax);
  if (lane == 0) sm[4+wv] = amax;
  __syncthreads();
  float gmax = fmaxf(fmaxf(sm[4],sm[5]), fmaxf(sm[6],sm[7]));
  float sc = 127.0f / fmaxf(gmax, 1e-5f);
  int2 o;
  char* oc = (char*)&o;
#pragma unroll
  for (int j = 0; j < 8; j++)
    oc[j] = (char)(int)fminf(fmaxf(rintf(h[j]*sc), -128.f), 127.f);
  *(int2*)(outq + (long)row*DIMC + tid*8) = o;
  if (tid == 0) rowdeq[row] = 1.0f / sc;
}

// ---------------- RoPE v2 (per-row LDS sincos table) + V transpose ----------------
__global__ __launch_bounds__(256) void k_ropevt2(u16* __restrict__ y,
                                                 const int* __restrict__ pos_ids,
                                                 u16* __restrict__ VT){
  if (blockIdx.x < 4096){
    const int m = blockIdx.x, tid = threadIdx.x;
    __shared__ float cs[64], sn[64];
    if (tid < 64){
      float pos = (float)pos_ids[m];
      float inv = expf((float)tid * -0.14391156831212787f);  // 10000^(-tid/64)
      float s, c;
      sincosf(pos * inv, &s, &c);
      cs[tid] = c; sn[tid] = s;
    }
    __syncthreads();
    u32* row = (u32*)(y + (long)m*QKV_N);
#pragma unroll
    for (int it = 0; it < 5; it++){
      int p = it*256 + tid;          // pair index < 1280 (cols [0,2560))
      int i = p & 63;
      u32 both = row[p];
      float x0 = bf2f((u16)(both & 0xffffu));
      float x1 = bf2f((u16)(both >> 16));
      float c = cs[i], s = sn[i];
      u16 o0 = f2bf(x0*c - x1*s);
      u16 o1 = f2bf(x1*c + x0*s);
      row[p] = (u32)o0 | ((u32)o1 << 16);
    }
  } else {
    int idx = (int)(blockIdx.x - 4096)*256 + threadIdx.x;  // < 262144
    int d  = idx & 127;
    int hk = (idx >> 7) & 3;
    int b  = (idx >> 9) & 1;
    int tg = idx >> 10;                       // 0..255
    int tok0 = tg*8;
    const u16* src = y + ((long)b*SEQ + tok0)*QKV_N + 2560 + hk*128 + d;
    u16 tmp[8];
#pragma unroll
    for (int e = 0; e < 8; e++) tmp[e] = src[(long)e*QKV_N];
    *(int4*)(VT + (((long)(b*4+hk))*128 + d)*SEQ + tok0) = *(int4*)tmp;
  }
}

// XCD-rectangle tile mapping (blocks with lin%8==x run on XCD x, empirical RR):
// each XCD owns a [nmt x xcdw] rectangle with ntl fastest, so the XCD's B panels
// (xcdw * BN rows) and the active A panel stay L2-resident (<= 4MiB working set),
// instead of every XCD streaming the whole B matrix (the R6 failure: 8x22.5MB).
// Requires vnt % 8 == 0; blocks with nt >= ntreal exit immediately.

// ---------------- GEMM v2: 256-wide tile, 8 waves, 4-phase K-loop, counted vmcnt ----
// (R1-proven sync schedule). i8 MFMA 16x16x64, BK=128.
// MODE 0: QKV -> bf16 + bias; MODE 1: fp32 = acc*rd*deq + resid.
template<int BM, int BN, int WM, int WN, int MODE>
__global__ __launch_bounds__(512, 2) void k_gemm8(
    const char* __restrict__ A, const char* __restrict__ B,
    int K, int lda, int ldb, int ldc, int vnt,
    const float* __restrict__ rowdeq, const float* __restrict__ deqp,
    const float* __restrict__ bq, const float* __restrict__ bk, const float* __restrict__ bv,
    const float* __restrict__ resid, float* __restrict__ outF, u16* __restrict__ outB)
{
  constexpr int SM = BM/WM, SN = BN/WN;       // per-wave output span
  constexpr int MR = SM/16, NR = SN/16, MRH = MR/2;
  constexpr int RA = BM/128, RB = BN/128;     // GLD16 rounds per region (512 thr)
  constexpr int ASZ = BM*64, BSZ = BN*64;     // one k-half region
  constexpr int BUFSZ = 2*(ASZ+BSZ);
  extern __shared__ __align__(16) char sm8[];

  const int tid = threadIdx.x;
  const int lane = tid & 63, wv = tid >> 6;
  const int wr = wv / WN, wc = wv % WN;
  const int r = lane & 15, qq = lane >> 4;

  // XCD-rectangle mapping (vnt % 8 == 0 for all k_gemm8 launches, no dead blocks)
  const int lin = blockIdx.x;
  const int xcd = lin & 7, i0 = lin >> 3;
  const int xcdw = vnt >> 3;
  const int ntl = i0 % xcdw, mt = i0 / xcdw;
  const int nt = xcd*xcdw + ntl;
  const long m0 = (long)mt*BM, n0 = (long)nt*BN;

  const char* __restrict__ gA = A + m0*lda;
  const char* __restrict__ gB = B + n0*ldb;

  // per-thread staging offsets (LDS linear slot c -> global group g = (c&3)^((row>>1)&3))
  int  soA[RA], soB[RB];
  long goA[RA], goB[RB];
#pragma unroll
  for (int u = 0; u < RA; u++){
    int c = u*512 + tid, row = c >> 2, gp = c & 3, g = gp ^ ((row>>1)&3);
    soA[u] = c*16; goA[u] = (long)row*lda + g*16;
  }
#pragma unroll
  for (int u = 0; u < RB; u++){
    int c = u*512 + tid, row = c >> 2, gp = c & 3, g = gp ^ ((row>>1)&3);
    soB[u] = c*16; goB[u] = (long)row*ldb + g*16;
  }
  // per-thread fragment-read offsets; (row>>1)&3 reduces to (r>>1)&3 here
  const int gsw = (qq ^ ((r>>1)&3))*16;
  const int aoff0 = (wr*SM + r)*64 + gsw;
  const int boff0 = (wc*SN + r)*64 + gsw;

  const int NT = K >> 7;

  i32x4 acc[MR][NR];
#pragma unroll
  for (int i = 0; i < MR; i++)
#pragma unroll
    for (int j = 0; j < NR; j++) acc[i][j] = (i32x4){0,0,0,0};

  auto stA = [&](int tq, int kh){
    char* dst = sm8 + (tq&1)*BUFSZ + kh*ASZ;
    const char* src = gA + (long)tq*128 + kh*64;
#pragma unroll
    for (int u = 0; u < RA; u++) GLD16(src + goA[u], dst + soA[u]);
  };
  auto stB = [&](int tq, int kh){
    char* dst = sm8 + (tq&1)*BUFSZ + 2*ASZ + kh*BSZ;
    const char* src = gB + (long)tq*128 + kh*64;
#pragma unroll
    for (int u = 0; u < RB; u++) GLD16(src + goB[u], dst + soB[u]);
  };

  // prologue: tile0 all regions, tile1 {A-k0, B-k0}; wait so tile0 landed,
  // tile1's first two regions remain in flight.
  stA(0,0); stB(0,0); stA(0,1); stB(0,1);
  stA(1,0); stB(1,0);
  if constexpr (RA+RB == 4) VMCNT(4); else VMCNT(3);
  SBAR();

  for (int t = 0; t < NT; t++){
    const char* cA = sm8 + (t&1)*BUFSZ;
    const char* cB = cA + 2*ASZ;
    i32x4 bF[NR];
    // ---- phase 0: m-half 0, k-half 0 ----
    {
      i32x4 aF[MRH];
#pragma unroll
      for (int i = 0; i < MRH; i++) aF[i] = *(const i32x4*)(cA + aoff0 + i*1024);
#pragma unroll
      for (int j = 0; j < NR; j++)  bF[j] = *(const i32x4*)(cB + boff0 + j*1024);
      if (t+1 < NT) stA(t+1, 1);
      SBAR();
      __builtin_amdgcn_s_setprio(1);
#pragma unroll
      for (int i = 0; i < MRH; i++)
#pragma unroll
        for (int j = 0; j < NR; j++)
          acc[i][j] = __builtin_amdgcn_mfma_i32_16x16x64_i8(aF[i], bF[j], acc[i][j], 0,0,0);
      __builtin_amdgcn_s_setprio(0);
      SBAR();
    }
    // ---- phase 1: m-half 1, k-half 0 (reuses bF) ----
    {
      i32x4 aF[MRH];
#pragma unroll
      for (int i = 0; i < MRH; i++) aF[i] = *(const i32x4*)(cA + aoff0 + (MRH+i)*1024);
      if (t+1 < NT) stB(t+1, 1);
      SBAR();
      __builtin_amdgcn_s_setprio(1);
#pragma unroll
      for (int i = 0; i < MRH; i++)
#pragma unroll
        for (int j = 0; j < NR; j++)
          acc[MRH+i][j] = __builtin_amdgcn_mfma_i32_16x16x64_i8(aF[i], bF[j], acc[MRH+i][j], 0,0,0);
      __builtin_amdgcn_s_setprio(0);
      SBAR();
    }
    // ---- phase 2: m-half 0, k-half 1 ----
    {
      i32x4 aF[MRH];
#pragma unroll
      for (int i = 0; i < MRH; i++) aF[i] = *(const i32x4*)(cA + ASZ + aoff0 + i*1024);
#pragma unroll
      for (int j = 0; j < NR; j++)  bF[j] = *(const i32x4*)(cB + BSZ + boff0 + j*1024);
      if (t+2 < NT) stA(t+2, 0);          // into CUR buf: A-k0 last read in ph1
      SBAR();
      __builtin_amdgcn_s_setprio(1);
#pragma unroll
      for (int i = 0; i < MRH; i++)
#pragma unroll
        for (int j = 0; j < NR; j++)
          acc[i][j] = __builtin_amdgcn_mfma_i32_16x16x64_i8(aF[i], bF[j], acc[i][j], 0,0,0);
      __builtin_amdgcn_s_setprio(0);
      SBAR();
    }
    // ---- phase 3: m-half 1, k-half 1 ----
    {
      i32x4 aF[MRH];
#pragma unroll
      for (int i = 0; i < MRH; i++) aF[i] = *(const i32x4*)(cA + ASZ + aoff0 + (MRH+i)*1024);
      if (t+2 < NT) stB(t+2, 0);          // into CUR buf: B-k0 last read in ph0
      SBAR();
      __builtin_amdgcn_s_setprio(1);
#pragma unroll
      for (int i = 0; i < MRH; i++)
#pragma unroll
        for (int j = 0; j < NR; j++)
          acc[MRH+i][j] = __builtin_amdgcn_mfma_i32_16x16x64_i8(aF[i], bF[j], acc[MRH+i][j], 0,0,0);
      __builtin_amdgcn_s_setprio(0);
      // tile boundary: ensure tile t+1 fully landed; keep t+2's first two
      // regions in flight (counted vmcnt, never 0 in steady state).
      if (t + 1 < NT){
        if (t + 2 < NT){ if constexpr (RA+RB == 4) VMCNT(4); else VMCNT(3); }
        else VMCNT(0);
      }
      SBAR();
    }
  }

  // epilogue
#pragma unroll
  for (int i = 0; i < MR; i++){
#pragma unroll
    for (int tt = 0; tt < 4; tt++){
      const long row = m0 + wr*SM + 16*i + 4*qq + tt;
      const float rdv = rowdeq[row];
#pragma unroll
      for (int j = 0; j < NR; j++){
        const long col = n0 + wc*SN + 16*j + r;
        float vv = (float)acc[i][j][tt];
        if constexpr (MODE == 0){
          int sec = (col >= 2048) + (col >= 2560);
          float dq = deqp[sec];
          float bias = (sec == 0) ? bq[col] : (sec == 1) ? bk[col-2048] : bv[col-2560];
          outB[row*(long)ldc + col] = f2bf(vv*rdv*dq + bias);
        } else {
          outF[row*(long)ldc + col] = vv*rdv*deqp[0] + resid[row*(long)ldc + col];
        }
      }
    }
  }
}

// ---------------- GEMM 2b (R2-proven sync structure): 256x128, 4 waves, 2 blocks/CU
// GU GEMM with FUSED SwiGLU epilogue (interleaved Wgu rows; writes h bf16).
template<int MODE>
__global__ __launch_bounds__(256, 2) void k_gemm2b(
    const char* __restrict__ A, const char* __restrict__ B,
    int K, int lda, int ldb, int ldc, int vnt, int ntreal,
    const float* __restrict__ rowdeq, const float* __restrict__ deqp,
    u16* __restrict__ outB)
{
  constexpr int BM = 256, BN = 128;
  constexpr int MR = 8, NR = 4, MRH = 4;      // wave-tile 128x64
  constexpr int RA = 4, RB = 2;               // GLD16 rounds (256 threads)
  constexpr int ASZ = BM*64, BSZ = BN*64;     // 16KB, 8KB
  constexpr int BUFSZ = ASZ + BSZ;            // 24KB
  __shared__ __align__(16) char sm8[2*BUFSZ]; // 48KB -> 2 blocks/CU

  const int tid = threadIdx.x;
  const int lane = tid & 63, wv = tid >> 6;   // 4 waves
  const int wr = wv >> 1, wc = wv & 1;        // 2x2 wave grid
  const int r = lane & 15, qq = lane >> 4;

  // XCD-rectangle mapping; vnt % 8 == 0, dead virtual blocks exit
  const int lin = blockIdx.x;
  const int xcd = lin & 7, i0 = lin >> 3;
  const int xcdw = vnt >> 3;
  const int ntl = i0 % xcdw, mt = i0 / xcdw;
  const int nt = xcd*xcdw + ntl;
  if (nt >= ntreal) return;
  const long m0 = (long)mt*BM, n0 = (long)nt*BN;

  const char* __restrict__ gA = A + m0*lda;
  const char* __restrict__ gB = B + n0*ldb;

  // staging offsets: LDS linear slot c -> global group g = (c&3)^((row>>1)&3)
  int  soA[RA], soB[RB];
  long goA[RA], goB[RB];
#pragma unroll
  for (int u = 0; u < RA; u++){
    int c = u*256 + tid, row = c >> 2, g = (c & 3) ^ ((row>>1)&3);
    soA[u] = c*16; goA[u] = (long)row*lda + g*16;
  }
#pragma unroll
  for (int u = 0; u < RB; u++){
    int c = u*256 + tid, row = c >> 2, g = (c & 3) ^ ((row>>1)&3);
    soB[u] = c*16; goB[u] = (long)row*ldb + g*16;
  }
  const int gsw = (qq ^ ((r>>1)&3))*16;
  const int aoff0 = (wr*128 + r)*64 + gsw;
  const int boff0 = (wc*64 + r)*64 + gsw;

  const int NT = K >> 6;

  i32x4 acc[MR][NR];
#pragma unroll
  for (int i = 0; i < MR; i++)
#pragma unroll
    for (int j = 0; j < NR; j++) acc[i][j] = (i32x4){0,0,0,0};

  auto stA = [&](int tq){
    char* dst = sm8 + (tq&1)*BUFSZ;
    const char* src = gA + (long)tq*64;
#pragma unroll
    for (int u = 0; u < RA; u++) GLD16(src + goA[u], dst + soA[u]);
  };
  auto stB = [&](int tq){
    char* dst = sm8 + (tq&1)*BUFSZ + ASZ;
    const char* src = gB + (long)tq*64;
#pragma unroll
    for (int u = 0; u < RB; u++) GLD16(src + goB[u], dst + soB[u]);
  };

  // prologue: A0[4] B0[2] B1[2] in flight; wait so A0,B0 landed, B1 flying.
  stA(0); stB(0); stB(1);
  VMCNT(2);
  SBAR();

  for (int t = 0; t < NT; t++){
    const char* cA = sm8 + (t&1)*BUFSZ;
    const char* cB = cA + ASZ;
    i32x4 bF[NR];
    // ---- phase 0: m-half 0 ----
    {
      i32x4 aF[MRH];
#pragma unroll
      for (int i = 0; i < MRH; i++) aF[i] = *(const i32x4*)(cA + aoff0 + i*1024);
#pragma unroll
      for (int j = 0; j < NR; j++)  bF[j] = *(const i32x4*)(cB + boff0 + j*1024);
      if (t+1 < NT) stA(t+1);               // into buf^1: its A reads ended tile t-1
      SBAR();
      __builtin_amdgcn_s_setprio(1);
#pragma unroll
      for (int i = 0; i < MRH; i++)
#pragma unroll
        for (int j = 0; j < NR; j++)
          acc[i][j] = __builtin_amdgcn_mfma_i32_16x16x64_i8(aF[i], bF[j], acc[i][j], 0,0,0);
      __builtin_amdgcn_s_setprio(0);
      SBAR();
    }
    // ---- phase 1: m-half 1 (reuses bF) ----
    {
      i32x4 aF[MRH];
#pragma unroll
      for (int i = 0; i < MRH; i++) aF[i] = *(const i32x4*)(cA + aoff0 + (MRH+i)*1024);
      if (t+2 < NT) stB(t+2);               // into cur buf: B(cur) reads ended ph0
      SBAR();
      __builtin_amdgcn_s_setprio(1);
#pragma unroll
      for (int i = 0; i < MRH; i++)
#pragma unroll
        for (int j = 0; j < NR; j++)
          acc[MRH+i][j] = __builtin_amdgcn_mfma_i32_16x16x64_i8(aF[i], bF[j], acc[MRH+i][j], 0,0,0);
      __builtin_amdgcn_s_setprio(0);
      // tile boundary: A(t+1),B(t+1) must land; B(t+2) stays in flight.
      if (t + 1 < NT){
        if (t + 2 < NT) VMCNT(2); else VMCNT(0);
      }
      SBAR();
    }
  }

  // epilogue: fused SwiGLU (MODE 3)
  const float dqg = deqp[0], dqu = deqp[1];
#pragma unroll
  for (int i = 0; i < MR; i++){
#pragma unroll
    for (int tt = 0; tt < 4; tt++){
      const long row = m0 + wr*128 + 16*i + 4*qq + tt;
      const float rdv = rowdeq[row];
#pragma unroll
      for (int j = 0; j < NR; j += 2){
        const long col = n0 + wc*64 + 16*j + r;       // gate col ((col>>4)&1 == 0)
        float g = (float)acc[i][j][tt]   * rdv * dqg;
        float u = (float)acc[i][j+1][tt] * rdv * dqu;
        float hv = g * (1.0f/(1.0f + __expf(-g))) * u;
        const long hcol = (col >> 5)*16 + (col & 15); // original SwiGLU column
        outB[row*(long)ldc + hcol] = f2bf(hv);
      }
    }
  }
}

// ---------------- flash attention v4: in-place pipelined, swizzled LDS ----------------
__global__ __launch_bounds__(256) void k_attn(const u16* __restrict__ Y,
                                              const u16* __restrict__ VT,
                                              float* __restrict__ O)
{
  __shared__ u16 Ks[64*128];     // [key][d], 16B group g stored at g^(key&7)
  __shared__ u16 VTs[128*64];    // [d][key], 16B group g stored at g^(d&7)
  __shared__ u16 Ps[64][72];     // P tile (wave-private rows, padded)

  const int pp = blockIdx.x;               // 0..15
  const int bh = blockIdx.y;
  const int b = bh >> 4, h = bh & 15, hk = h >> 2;
  const int tid = threadIdx.x;
  const int lane = tid & 63, wv = tid >> 6;
  const int r = lane & 15, qq = lane >> 4;
  const long rowbase = (long)b * SEQ;
  const u16* Kbase = Y + rowbase*QKV_N + 2048 + hk*128;
  const u16* Vbase = VT + ((long)(b*4+hk))*128*SEQ;

  for (int ph = 0; ph < 2; ph++){
    const int qt = ph ? pp : 31 - pp;
    const int q0 = qt * 64;

    // Q A-fragments: 16B-contiguous in global, load direct (no LDS)
    bf16x8 qf[4];
#pragma unroll
    for (int kc = 0; kc < 4; kc++)
      qf[kc] = *(const bf16x8*)(Y + (rowbase + q0 + wv*16 + r)*QKV_N + h*128 + kc*32 + qq*8);

    // preload tile 0
#pragma unroll
    for (int rnd = 0; rnd < 4; rnd++){
      int c = rnd*256 + tid;
      int row = c >> 4, g = (c & 15) ^ (row & 7);
      GLD16(Kbase + ((long)(qt*0 + row))*QKV_N + g*8, (char*)Ks + c*16);
    }
#pragma unroll
    for (int rnd = 0; rnd < 4; rnd++){
      int c = rnd*256 + tid;
      int d = c >> 3, g = (c & 7) ^ (d & 7);
      GLD16(Vbase + (long)d*SEQ + g*8, (char*)VTs + c*16);
    }
    __syncthreads();

    f32x4 accO[8];
#pragma unroll
    for (int jn = 0; jn < 8; jn++) accO[jn] = (f32x4){0.f,0.f,0.f,0.f};
    float m_run[4] = {-INFINITY,-INFINITY,-INFINITY,-INFINITY};
    float l_run[4] = {0.f,0.f,0.f,0.f};

    for (int kt = 0; kt <= qt; kt++){
      // S = Q K^T
      float sv[4][4];
#pragma unroll
      for (int j = 0; j < 4; j++){
        f32x4 a = (f32x4){0.f,0.f,0.f,0.f};
#pragma unroll
        for (int kc = 0; kc < 4; kc++){
          bf16x8 kf = *(const bf16x8*)(Ks + (16*j + r)*128 + (((kc*4 + qq) ^ (r & 7)))*8);
          a = __builtin_amdgcn_mfma_f32_16x16x32_bf16(qf[kc], kf, a, 0, 0, 0);
        }
#pragma unroll
        for (int t = 0; t < 4; t++) sv[j][t] = a[t] * ATT_SCALE;
      }
      __syncthreads();                       // bar1: Ks free; drains V(kt) of prev iter
      if (kt < qt){                          // issue K(kt+1); flies during softmax+PV
#pragma unroll
        for (int rnd = 0; rnd < 4; rnd++){
          int c = rnd*256 + tid;
          int row = c >> 4, g = (c & 15) ^ (row & 7);
          GLD16(Kbase + ((long)((kt+1)*64 + row))*QKV_N + g*8, (char*)Ks + c*16);
        }
      }
      if (kt == qt){
#pragma unroll
        for (int j = 0; j < 4; j++){
          int key = kt*64 + 16*j + r;
#pragma unroll
          for (int t = 0; t < 4; t++){
            int qr = q0 + wv*16 + 4*qq + t;
            if (key > qr) sv[j][t] = -INFINITY;
          }
        }
      }
      // online softmax per q-row (wave-private rows)
#pragma unroll
      for (int t = 0; t < 4; t++){
        float mm = fmaxf(fmaxf(sv[0][t],sv[1][t]), fmaxf(sv[2][t],sv[3][t]));
#pragma unroll
        for (int o = 8; o > 0; o >>= 1) mm = fmaxf(mm, __shfl_xor(mm, o));
        float mnew = fmaxf(m_run[t], mm);
        float alpha = __expf(m_run[t] - mnew);
        m_run[t] = mnew;
        float ps = 0.f;
#pragma unroll
        for (int j = 0; j < 4; j++){
          float p = __expf(sv[j][t] - mnew);
          ps += p;
          Ps[wv*16 + 4*qq + t][16*j + r] = f2bf(p);
        }
#pragma unroll
        for (int o = 8; o > 0; o >>= 1) ps += __shfl_xor(ps, o);
        l_run[t] = l_run[t]*alpha + ps;
#pragma unroll
        for (int jn = 0; jn < 8; jn++) accO[jn][t] *= alpha;
      }
      // O += P V
#pragma unroll
      for (int kc = 0; kc < 2; kc++){
        bf16x8 pf = *(const bf16x8*)&Ps[wv*16 + r][kc*32 + qq*8];
#pragma unroll
        for (int jn = 0; jn < 8; jn++){
          bf16x8 vf = *(const bf16x8*)(VTs + (16*jn + r)*64 + (((kc*4 + qq) ^ (r & 7)))*8);
          accO[jn] = __builtin_amdgcn_mfma_f32_16x16x32_bf16(pf, vf, accO[jn], 0, 0, 0);
        }
      }
      __syncthreads();                       // bar2: VTs free; drains K(kt+1)
      if (kt < qt){                          // issue V(kt+1); flies during next S
#pragma unroll
        for (int rnd = 0; rnd < 4; rnd++){
          int c = rnd*256 + tid;
          int d = c >> 3, g = (c & 7) ^ (d & 7);
          GLD16(Vbase + (long)d*SEQ + (kt+1)*64 + g*8, (char*)VTs + c*16);
        }
      }
    }
    float inv[4];
#pragma unroll
    for (int t = 0; t < 4; t++) inv[t] = 1.0f / l_run[t];
#pragma unroll
    for (int jn = 0; jn < 8; jn++){
#pragma unroll
      for (int t = 0; t < 4; t++){
        long row = rowbase + q0 + wv*16 + 4*qq + t;
        O[row*DIMC + h*128 + 16*jn + r] = accO[jn][t]*inv[t];
      }
    }
    __syncthreads();   // protect Ks/VTs before next phase preload
  }
}

// ---------------- h bf16 [4096][5504] -> act_quant i8 ----------------
__global__ __launch_bounds__(256) void k_hquant(const u16* __restrict__ hbuf,
                                                char* __restrict__ qout,
                                                float* __restrict__ rowdeq){
  const int row = blockIdx.x, tid = threadIdx.x;
  const u16* base = hbuf + (long)row * MLP_P;
  float h[24];
  float amax = 0.f;
#pragma unroll
  for (int it = 0; it < 3; it++){
    int chunk = it*256 + tid;
    if (chunk < 688){
      int j0 = chunk*8;
      int4 h4 = *(const int4*)(base + j0);
      const u16* hp = (const u16*)&h4;
#pragma unroll
      for (int e = 0; e < 8; e++){
        float hv = bf2f(hp[e]);
        h[it*8+e] = hv;
        amax = fmaxf(amax, fabsf(hv));
      }
    } else {
#pragma unroll
      for (int e = 0; e < 8; e++) h[it*8+e] = 0.f;
    }
  }
  amax = waveRedMax(amax);
  __shared__ float sm[4];
  int lane = tid & 63, wv = tid >> 6;
  if (lane == 0) sm[wv] = amax;
  __syncthreads();
  float gmax = fmaxf(fmaxf(sm[0],sm[1]), fmaxf(sm[2],sm[3]));
  float sc = 127.0f / fmaxf(gmax, 1e-5f);
#pragma unroll
  for (int it = 0; it < 3; it++){
    int chunk = it*256 + tid;
    if (chunk < 688){
      int j0 = chunk*8;
      int2 o;
      char* oc = (char*)&o;
#pragma unroll
      for (int e = 0; e < 8; e++)
        oc[e] = (char)(int)fminf(fmaxf(rintf(h[it*8+e]*sc), -128.f), 127.f);
      *(int2*)(qout + (long)row*MLP_P + j0) = o;
    }
  }
  if (tid == 0) rowdeq[row] = 1.0f/sc;
}

extern "C" void kernel_launch(void* const* d_in, const int* in_sizes, int n_in,
                              void* d_out, int out_size, void* d_ws, size_t ws_size,
                              hipStream_t stream)
{
  (void)in_sizes; (void)n_in; (void)out_size; (void)ws_size;
  const float* x   = (const float*)d_in[0];
  const int*   pos = (const int*)d_in[1];
  const float* n1w = (const float*)d_in[2];
  const float* qw  = (const float*)d_in[3];
  const float* qb  = (const float*)d_in[4];
  const float* kw  = (const float*)d_in[5];
  const float* kb  = (const float*)d_in[6];
  const float* vw  = (const float*)d_in[7];
  const float* vb  = (const float*)d_in[8];
  const float* ow  = (const float*)d_in[9];
  const float* n2w = (const float*)d_in[10];
  const float* gw  = (const float*)d_in[11];
  const float* uw  = (const float*)d_in[12];
  const float* dw  = (const float*)d_in[13];
  float* out = (float*)d_out;
  char* ws = (char*)d_ws;

  // one-time: allow >64KB dynamic LDS for the k_gemm8 instantiations
  static int attr_done = 0;
  if (!attr_done){
    hipFuncSetAttribute(reinterpret_cast<const void*>(k_gemm8<256,128,4,2,0>),
                        hipFuncAttributeMaxDynamicSharedMemorySize, 98304);
    hipFuncSetAttribute(reinterpret_cast<const void*>(k_gemm8<256,128,4,2,1>),
                        hipFuncAttributeMaxDynamicSharedMemorySize, 98304);
    attr_done = 1;
  }

  // workspace layout (all offsets multiple of 256)
  float* sc   = (float*)ws;                 // [0..6] sums, [8..14] deq
  char* Wqkv  = ws + 256;                   // [3072][2048] i8   (6.29 MB)
  char* Wo    = ws + 6291712;               // [2048][2048] i8   (4.19 MB)
  char* Wgu   = ws + 10486016;              // [11008][2048] i8 interleaved (22.5 MB)
  char* Wd    = ws + 33030400;              // [2048][5504] i8   (11.3 MB)
  char* actq  = ws + 44302592;              // [4096][2048] i8   (8.39 MB)
  char* swq   = ws + 52691200;              // [4096][5504] i8   (22.5 MB)
  float* rd   = (float*)(ws + 75235584);    // [4096] fp32
  char* xreg  = ws + 75252224;              // overlay region (90.2 MB)
  u16* yqkv   = (u16*)xreg;                 // [4096][3072] bf16 (25.2 MB)
  float* attn = (float*)(xreg + 25165824);  // [4096][2048] fp32 (33.6 MB)
  u16* vT     = (u16*)(xreg + 58720256);    // [8][128][2048] bf16 (8.4 MB)
  u16* hbuf   = (u16*)xreg;                 // [4096][5504] bf16 (45.1 MB, after attention)

  // ---- weight scales + ternary i8 quant (fused dispatches) ----
  hipMemsetAsync(sc, 0, 64, stream);
  hipMemsetAsync(Wgu, 0, 11008l*2048, stream);   // zero pads for interleaved layout
  k_abssum7<<<dim3(512,7),256,0,stream>>>((const float4*)qw, (const float4*)kw,
                                          (const float4*)vw, (const float4*)ow,
                                          (const float4*)gw, (const float4*)uw,
                                          (const float4*)dw, sc);
  k_finalize<<<1,64,0,stream>>>(sc);
  k_wquant6<<<dim3(512,6),256,0,stream>>>((const float4*)qw, (const float4*)kw,
                                          (const float4*)vw, (const float4*)ow,
                                          (const float4*)gw, (const float4*)uw,
                                          (u32*)Wqkv, (u32*)(Wqkv + 2048l*2048),
                                          (u32*)(Wqkv + 2560l*2048), (u32*)Wo,
                                          (u32*)Wgu, sc);
  k_wquant_down<<<11008,256,0,stream>>>(dw, (u32*)Wd, sc+14);

  // ---- attention half ----
  k_rmsq<<<4096,256,0,stream>>>(x, n1w, actq, rd, 1);
  k_gemm8<256,128,4,2,0><<<384,512,98304,stream>>>(actq, Wqkv, 2048, 2048, 2048, 3072, 24,
                                          rd, sc+8, qb, kb, vb, nullptr, nullptr, yqkv);
  k_ropevt2<<<5120,256,0,stream>>>(yqkv, pos, vT);
  k_attn<<<dim3(16,32),256,0,stream>>>(yqkv, vT, attn);
  k_rmsq<<<4096,256,0,stream>>>(attn, n1w, actq, rd, 0);
  k_gemm8<256,128,4,2,1><<<256,512,98304,stream>>>(actq, Wo, 2048, 2048, 2048, 2048, 16,
                                          rd, sc+11, nullptr, nullptr, nullptr, x, out, nullptr);

  // ---- MLP half (x1 lives in d_out) ----
  k_rmsq<<<4096,256,0,stream>>>(out, n2w, actq, rd, 1);
  k_gemm2b<3><<<1408,256,0,stream>>>(actq, Wgu, 2048, 2048, 2048, MLP_P, 88, 86,
                                     rd, sc+12, hbuf);
  k_hquant<<<4096,256,0,stream>>>(hbuf, swq, rd);
  k_gemm8<256,128,4,2,1><<<256,512,98304,stream>>>(swq, Wd, 5504, 5504, 5504, 2048, 16,
                                          rd, sc+14, nullptr, nullptr, nullptr, out, out, nullptr);
}

// Round 8
// 673.478 us; speedup vs baseline: 1.0298x; 1.0298x over previous
//
#include <hip/hip_runtime.h>

typedef unsigned short u16;
typedef unsigned int   u32;
typedef unsigned char  u8;

using bf16x8 = __attribute__((ext_vector_type(8))) short;
using f32x4  = __attribute__((ext_vector_type(4))) float;
using i32x4  = __attribute__((ext_vector_type(4))) int;

#define SEQ    2048
#define DIMC   2048
#define TOK    4096
#define QKV_N  3072
#define GU_N   11008
#define MLP_P  5504
#define MLP_R  5461
#define ATT_SCALE 0.08838834764831845f

__device__ __forceinline__ float bf2f(u16 v){ return __uint_as_float(((u32)v) << 16); }
__device__ __forceinline__ u16 f2bf(float f){
  u32 x = __float_as_uint(f);
  u32 r = (x + 0x7fffu + ((x >> 16) & 1u)) >> 16;
  return (u16)r;
}

__device__ __forceinline__ float waveRedSum(float v){
#pragma unroll
  for (int o = 32; o > 0; o >>= 1) v += __shfl_xor(v, o);
  return v;
}
__device__ __forceinline__ float waveRedMax(float v){
#pragma unroll
  for (int o = 32; o > 0; o >>= 1) v = fmaxf(v, __shfl_xor(v, o));
  return v;
}

// async global->LDS, 16B per lane. LDS dest is wave-uniform base + lane*16.
#define GLD16(gp, lp) __builtin_amdgcn_global_load_lds( \
    (__attribute__((address_space(1))) void*)(gp), \
    (__attribute__((address_space(3))) void*)(lp), 16, 0, 0)

#define FENCE() asm volatile("" ::: "memory")
#define SBAR()  do{ FENCE(); __builtin_amdgcn_s_barrier(); FENCE(); }while(0)
#define VMCNT(n) asm volatile("s_waitcnt vmcnt(" #n ")" ::: "memory")

// ---------------- fused weight abs-sums (7 regions in one dispatch) ----------------
__global__ __launch_bounds__(256) void k_abssum7(
    const float4* __restrict__ w0, const float4* __restrict__ w1,
    const float4* __restrict__ w2, const float4* __restrict__ w3,
    const float4* __restrict__ w4, const float4* __restrict__ w5,
    const float4* __restrict__ w6, float* __restrict__ sc){
  const int rg = blockIdx.y;
  const float4* w = rg==0?w0: rg==1?w1: rg==2?w2: rg==3?w3: rg==4?w4: rg==5?w5: w6;
  const int n4 = (rg==0||rg==3) ? 1048576 : (rg<4 ? 262144 : 2796032);
  float s = 0.f;
  for (int i = blockIdx.x*256 + threadIdx.x; i < n4; i += gridDim.x*256){
    float4 v = w[i];
    s += fabsf(v.x) + fabsf(v.y) + fabsf(v.z) + fabsf(v.w);
  }
  s = waveRedSum(s);
  __shared__ float sm[4];
  int lane = threadIdx.x & 63, wv = threadIdx.x >> 6;
  if (lane == 0) sm[wv] = s;
  __syncthreads();
  if (threadIdx.x == 0) atomicAdd(sc + rg, sm[0]+sm[1]+sm[2]+sm[3]);
}

// sums at sc[0..6] -> deq (=clip(mean,1e-5)) at sc[8..14]
__global__ void k_finalize(float* __restrict__ sc){
  if (threadIdx.x == 0){
    const float counts[7] = {4194304.f, 1048576.f, 1048576.f, 4194304.f,
                             11184128.f, 11184128.f, 11184128.f};
    for (int i = 0; i < 7; i++) sc[8+i] = fmaxf(sc[i]/counts[i], 1e-5f);
  }
}

// ---------------- fused ternary weight quant (6 regions) -> packed i8 ----------------
// Regions 4 (gate) and 5 (up) are written INTERLEAVED into Wgu:
//   gate row j -> Wgu row 32*(j>>4) + (j&15)
//   up   row j -> Wgu row 32*(j>>4) + 16 + (j&15)
__global__ __launch_bounds__(256) void k_wquant6(
    const float4* __restrict__ w0, const float4* __restrict__ w1,
    const float4* __restrict__ w2, const float4* __restrict__ w3,
    const float4* __restrict__ w4, const float4* __restrict__ w5,
    u32* __restrict__ d0, u32* __restrict__ d1, u32* __restrict__ d2,
    u32* __restrict__ d3, u32* __restrict__ dgu,
    const float* __restrict__ sc){
  const int rg = blockIdx.y;
  const float4* src = rg==0?w0: rg==1?w1: rg==2?w2: rg==3?w3: rg==4?w4: w5;
  const int n4 = (rg==0||rg==3) ? 1048576 : (rg<4 ? 262144 : 2796032);
  float ws = 1.0f / sc[8+rg];
  for (int i = blockIdx.x*256 + threadIdx.x; i < n4; i += gridDim.x*256){
    float4 v = src[i];
    int c0 = (int)fminf(fmaxf(rintf(v.x*ws), -1.f), 1.f);
    int c1 = (int)fminf(fmaxf(rintf(v.y*ws), -1.f), 1.f);
    int c2 = (int)fminf(fmaxf(rintf(v.z*ws), -1.f), 1.f);
    int c3 = (int)fminf(fmaxf(rintf(v.w*ws), -1.f), 1.f);
    u32 pk = (u32)(u8)c0 | ((u32)(u8)c1 << 8) | ((u32)(u8)c2 << 16) | ((u32)(u8)c3 << 24);
    if (rg < 4){
      u32* dst = rg==0?d0: rg==1?d1: rg==2?d2: d3;
      dst[i] = pk;
    } else {
      int row = i >> 9, col = i & 511;            // 512 u32 per 2048-col row
      int rI = 32*(row>>4) + (row&15) + ((rg==5)?16:0);
      dgu[(long)rI*512 + col] = pk;
    }
  }
}

// down_w [2048][5461] fp32 -> [2048][5504] i8 padded with zeros
__global__ __launch_bounds__(256) void k_wquant_down(const float* __restrict__ src,
                                                     u32* __restrict__ dst,
                                                     const float* __restrict__ deqp){
  int i = blockIdx.x*256 + threadIdx.x;
  const int total = 2048*(MLP_P/4);
  if (i >= total) return;
  float ws = 1.0f / deqp[0];
  int r = i / (MLP_P/4);
  int c4 = (i - r*(MLP_P/4))*4;
  u32 o = 0;
#pragma unroll
  for (int e = 0; e < 4; e++){
    int c = c4 + e;
    int t = 0;
    if (c < MLP_R) t = (int)fminf(fmaxf(rintf(src[(long)r*MLP_R + c]*ws), -1.f), 1.f);
    o |= (u32)(u8)t << (8*e);
  }
  dst[i] = o;
}

// ---------------- rmsnorm (optional) + act_quant over 2048 fp32 -> i8 ----------------
__global__ __launch_bounds__(256) void k_rmsq(const float* __restrict__ in,
                                              const float* __restrict__ nw,
                                              char* __restrict__ outq,
                                              float* __restrict__ rowdeq, int do_norm){
  const int row = blockIdx.x, tid = threadIdx.x;
  const float* xp = in + (long)row * DIMC + tid*8;
  float v[8];
  float4 a0 = *(const float4*)xp;
  float4 a1 = *(const float4*)(xp + 4);
  v[0]=a0.x; v[1]=a0.y; v[2]=a0.z; v[3]=a0.w;
  v[4]=a1.x; v[5]=a1.y; v[6]=a1.z; v[7]=a1.w;
  float ss = 0.f;
#pragma unroll
  for (int j = 0; j < 8; j++) ss += v[j]*v[j];
  __shared__ float sm[8];
  int lane = tid & 63, wv = tid >> 6;
  ss = waveRedSum(ss);
  if (lane == 0) sm[wv] = ss;
  __syncthreads();
  float h[8];
  float amax = 0.f;
  if (do_norm){
    float tot = sm[0]+sm[1]+sm[2]+sm[3];
    float rms = rsqrtf(tot * (1.0f/DIMC) + 1.1920929e-07f);
    float4 w0 = *(const float4*)(nw + tid*8);
    float4 w1 = *(const float4*)(nw + tid*8 + 4);
    float wr8[8] = {w0.x,w0.y,w0.z,w0.w,w1.x,w1.y,w1.z,w1.w};
#pragma unroll
    for (int j = 0; j < 8; j++){ h[j] = v[j]*rms*wr8[j]; amax = fmaxf(amax, fabsf(h[j])); }
  } else {
#pragma unroll
    for (int j = 0; j < 8; j++){ h[j] = v[j]; amax = fmaxf(amax, fabsf(h[j])); }
  }
  amax = waveRedMax(amax);
  if (lane == 0) sm[4+wv] = amax;
  __syncthreads();
  float gmax = fmaxf(fmaxf(sm[4],sm[5]), fmaxf(sm[6],sm[7]));
  float sc = 127.0f / fmaxf(gmax, 1e-5f);
  int2 o;
  char* oc = (char*)&o;
#pragma unroll
  for (int j = 0; j < 8; j++)
    oc[j] = (char)(int)fminf(fmaxf(rintf(h[j]*sc), -128.f), 127.f);
  *(int2*)(outq + (long)row*DIMC + tid*8) = o;
  if (tid == 0) rowdeq[row] = 1.0f / sc;
}

// ---------------- act_quant over 2048 bf16 -> i8 (attention output) ----------------
__global__ __launch_bounds__(256) void k_quantb(const u16* __restrict__ in,
                                                char* __restrict__ outq,
                                                float* __restrict__ rowdeq){
  const int row = blockIdx.x, tid = threadIdx.x;
  int4 a = *(const int4*)(in + (long)row*DIMC + tid*8);
  const u16* ap = (const u16*)&a;
  float v[8];
  float amax = 0.f;
#pragma unroll
  for (int j = 0; j < 8; j++){ v[j] = bf2f(ap[j]); amax = fmaxf(amax, fabsf(v[j])); }
  amax = waveRedMax(amax);
  __shared__ float sm[4];
  int lane = tid & 63, wv = tid >> 6;
  if (lane == 0) sm[wv] = amax;
  __syncthreads();
  float gmax = fmaxf(fmaxf(sm[0],sm[1]), fmaxf(sm[2],sm[3]));
  float sc = 127.0f / fmaxf(gmax, 1e-5f);
  int2 o;
  char* oc = (char*)&o;
#pragma unroll
  for (int j = 0; j < 8; j++)
    oc[j] = (char)(int)fminf(fmaxf(rintf(v[j]*sc), -128.f), 127.f);
  *(int2*)(outq + (long)row*DIMC + tid*8) = o;
  if (tid == 0) rowdeq[row] = 1.0f / sc;
}

// ---------------- RoPE v2 (per-row LDS sincos table) + V transpose ----------------
__global__ __launch_bounds__(256) void k_ropevt2(u16* __restrict__ y,
                                                 const int* __restrict__ pos_ids,
                                                 u16* __restrict__ VT){
  if (blockIdx.x < 4096){
    const int m = blockIdx.x, tid = threadIdx.x;
    __shared__ float cs[64], sn[64];
    if (tid < 64){
      float pos = (float)pos_ids[m];
      float inv = expf((float)tid * -0.14391156831212787f);  // 10000^(-tid/64)
      float s, c;
      sincosf(pos * inv, &s, &c);
      cs[tid] = c; sn[tid] = s;
    }
    __syncthreads();
    u32* row = (u32*)(y + (long)m*QKV_N);
#pragma unroll
    for (int it = 0; it < 5; it++){
      int p = it*256 + tid;          // pair index < 1280 (cols [0,2560))
      int i = p & 63;
      u32 both = row[p];
      float x0 = bf2f((u16)(both & 0xffffu));
      float x1 = bf2f((u16)(both >> 16));
      float c = cs[i], s = sn[i];
      u16 o0 = f2bf(x0*c - x1*s);
      u16 o1 = f2bf(x1*c + x0*s);
      row[p] = (u32)o0 | ((u32)o1 << 16);
    }
  } else {
    int idx = (int)(blockIdx.x - 4096)*256 + threadIdx.x;  // < 262144
    int d  = idx & 127;
    int hk = (idx >> 7) & 3;
    int b  = (idx >> 9) & 1;
    int tg = idx >> 10;                       // 0..255
    int tok0 = tg*8;
    const u16* src = y + ((long)b*SEQ + tok0)*QKV_N + 2560 + hk*128 + d;
    u16 tmp[8];
#pragma unroll
    for (int e = 0; e < 8; e++) tmp[e] = src[(long)e*QKV_N];
    *(int4*)(VT + (((long)(b*4+hk))*128 + d)*SEQ + tok0) = *(int4*)tmp;
  }
}

// ---------------- GEMM v2: 256-wide tile, 8 waves, 4-phase K-loop, counted vmcnt ----
// (R1-proven schedule + R6-proven chunked XCD swizzle). i8 MFMA 16x16x64, BK=128.
// MODE 0: QKV -> bf16 + bias.
template<int BM, int BN, int WM, int WN, int MODE>
__global__ __launch_bounds__(512, 2) void k_gemm8(
    const char* __restrict__ A, const char* __restrict__ B,
    int K, int lda, int ldb, int ldc, int ntn,
    const float* __restrict__ rowdeq, const float* __restrict__ deqp,
    const float* __restrict__ bq, const float* __restrict__ bk, const float* __restrict__ bv,
    const float* __restrict__ resid, float* __restrict__ outF, u16* __restrict__ outB)
{
  constexpr int SM = BM/WM, SN = BN/WN;       // per-wave output span
  constexpr int MR = SM/16, NR = SN/16, MRH = MR/2;
  constexpr int RA = BM/128, RB = BN/128;     // GLD16 rounds per region (512 thr)
  constexpr int ASZ = BM*64, BSZ = BN*64;     // one k-half region
  constexpr int BUFSZ = 2*(ASZ+BSZ);
  extern __shared__ __align__(16) char sm8[];

  const int tid = threadIdx.x;
  const int lane = tid & 63, wv = tid >> 6;
  const int wr = wv / WN, wc = wv % WN;
  const int r = lane & 15, qq = lane >> 4;

  // chunked bijective XCD swizzle (gridDim.x % 8 == 0)
  const int nwg = gridDim.x;
  const int chunk = nwg >> 3;
  const int lin = blockIdx.x;
  const int swz = (lin & 7)*chunk + (lin >> 3);
  const int mt = swz / ntn, nt = swz - mt*ntn;
  const long m0 = (long)mt*BM, n0 = (long)nt*BN;

  const char* __restrict__ gA = A + m0*lda;
  const char* __restrict__ gB = B + n0*ldb;

  // per-thread staging offsets (LDS linear slot c -> global group g = (c&3)^((row>>1)&3))
  int  soA[RA], soB[RB];
  long goA[RA], goB[RB];
#pragma unroll
  for (int u = 0; u < RA; u++){
    int c = u*512 + tid, row = c >> 2, gp = c & 3, g = gp ^ ((row>>1)&3);
    soA[u] = c*16; goA[u] = (long)row*lda + g*16;
  }
#pragma unroll
  for (int u = 0; u < RB; u++){
    int c = u*512 + tid, row = c >> 2, gp = c & 3, g = gp ^ ((row>>1)&3);
    soB[u] = c*16; goB[u] = (long)row*ldb + g*16;
  }
  // per-thread fragment-read offsets; (row>>1)&3 reduces to (r>>1)&3 here
  const int gsw = (qq ^ ((r>>1)&3))*16;
  const int aoff0 = (wr*SM + r)*64 + gsw;
  const int boff0 = (wc*SN + r)*64 + gsw;

  const int NT = K >> 7;

  i32x4 acc[MR][NR];
#pragma unroll
  for (int i = 0; i < MR; i++)
#pragma unroll
    for (int j = 0; j < NR; j++) acc[i][j] = (i32x4){0,0,0,0};

  auto stA = [&](int tq, int kh){
    char* dst = sm8 + (tq&1)*BUFSZ + kh*ASZ;
    const char* src = gA + (long)tq*128 + kh*64;
#pragma unroll
    for (int u = 0; u < RA; u++) GLD16(src + goA[u], dst + soA[u]);
  };
  auto stB = [&](int tq, int kh){
    char* dst = sm8 + (tq&1)*BUFSZ + 2*ASZ + kh*BSZ;
    const char* src = gB + (long)tq*128 + kh*64;
#pragma unroll
    for (int u = 0; u < RB; u++) GLD16(src + goB[u], dst + soB[u]);
  };

  // prologue
  stA(0,0); stB(0,0); stA(0,1); stB(0,1);
  stA(1,0); stB(1,0);
  if constexpr (RA+RB == 4) VMCNT(4); else VMCNT(3);
  SBAR();

  for (int t = 0; t < NT; t++){
    const char* cA = sm8 + (t&1)*BUFSZ;
    const char* cB = cA + 2*ASZ;
    i32x4 bF[NR];
    // ---- phase 0: m-half 0, k-half 0 ----
    {
      i32x4 aF[MRH];
#pragma unroll
      for (int i = 0; i < MRH; i++) aF[i] = *(const i32x4*)(cA + aoff0 + i*1024);
#pragma unroll
      for (int j = 0; j < NR; j++)  bF[j] = *(const i32x4*)(cB + boff0 + j*1024);
      if (t+1 < NT) stA(t+1, 1);
      SBAR();
      __builtin_amdgcn_s_setprio(1);
#pragma unroll
      for (int i = 0; i < MRH; i++)
#pragma unroll
        for (int j = 0; j < NR; j++)
          acc[i][j] = __builtin_amdgcn_mfma_i32_16x16x64_i8(aF[i], bF[j], acc[i][j], 0,0,0);
      __builtin_amdgcn_s_setprio(0);
      SBAR();
    }
    // ---- phase 1: m-half 1, k-half 0 ----
    {
      i32x4 aF[MRH];
#pragma unroll
      for (int i = 0; i < MRH; i++) aF[i] = *(const i32x4*)(cA + aoff0 + (MRH+i)*1024);
      if (t+1 < NT) stB(t+1, 1);
      SBAR();
      __builtin_amdgcn_s_setprio(1);
#pragma unroll
      for (int i = 0; i < MRH; i++)
#pragma unroll
        for (int j = 0; j < NR; j++)
          acc[MRH+i][j] = __builtin_amdgcn_mfma_i32_16x16x64_i8(aF[i], bF[j], acc[MRH+i][j], 0,0,0);
      __builtin_amdgcn_s_setprio(0);
      SBAR();
    }
    // ---- phase 2: m-half 0, k-half 1 ----
    {
      i32x4 aF[MRH];
#pragma unroll
      for (int i = 0; i < MRH; i++) aF[i] = *(const i32x4*)(cA + ASZ + aoff0 + i*1024);
#pragma unroll
      for (int j = 0; j < NR; j++)  bF[j] = *(const i32x4*)(cB + BSZ + boff0 + j*1024);
      if (t+2 < NT) stA(t+2, 0);
      SBAR();
      __builtin_amdgcn_s_setprio(1);
#pragma unroll
      for (int i = 0; i < MRH; i++)
#pragma unroll
        for (int j = 0; j < NR; j++)
          acc[i][j] = __builtin_amdgcn_mfma_i32_16x16x64_i8(aF[i], bF[j], acc[i][j], 0,0,0);
      __builtin_amdgcn_s_setprio(0);
      SBAR();
    }
    // ---- phase 3: m-half 1, k-half 1 ----
    {
      i32x4 aF[MRH];
#pragma unroll
      for (int i = 0; i < MRH; i++) aF[i] = *(const i32x4*)(cA + ASZ + aoff0 + (MRH+i)*1024);
      if (t+2 < NT) stB(t+2, 0);
      SBAR();
      __builtin_amdgcn_s_setprio(1);
#pragma unroll
      for (int i = 0; i < MRH; i++)
#pragma unroll
        for (int j = 0; j < NR; j++)
          acc[MRH+i][j] = __builtin_amdgcn_mfma_i32_16x16x64_i8(aF[i], bF[j], acc[MRH+i][j], 0,0,0);
      __builtin_amdgcn_s_setprio(0);
      if (t + 1 < NT){
        if (t + 2 < NT){ if constexpr (RA+RB == 4) VMCNT(4); else VMCNT(3); }
        else VMCNT(0);
      }
      SBAR();
    }
  }

  // epilogue
#pragma unroll
  for (int i = 0; i < MR; i++){
#pragma unroll
    for (int tt = 0; tt < 4; tt++){
      const long row = m0 + wr*SM + 16*i + 4*qq + tt;
      const float rdv = rowdeq[row];
#pragma unroll
      for (int j = 0; j < NR; j++){
        const long col = n0 + wc*SN + 16*j + r;
        float vv = (float)acc[i][j][tt];
        if constexpr (MODE == 0){
          int sec = (col >= 2048) + (col >= 2560);
          float dq = deqp[sec];
          float bias = (sec == 0) ? bq[col] : (sec == 1) ? bk[col-2048] : bv[col-2560];
          outB[row*(long)ldc + col] = f2bf(vv*rdv*dq + bias);
        } else {
          outF[row*(long)ldc + col] = vv*rdv*deqp[0] + resid[row*(long)ldc + col];
        }
      }
    }
  }
}

// ---------------- GEMM 2b (R2/R6-proven sync structure): BMx128, 4 waves ----------
// BM=256 (MODE 3, GU+fused SwiGLU): 48KB LDS -> 2 blocks/CU, XCD-rect mapping.
// BM=128 (MODE 1, O/Down): 32KB LDS, 64-AGPR acc -> 3 blocks/CU anti-phased,
// chunked swizzle. Identical vmcnt literals (boundary outstanding = RB = 2).
template<int BM, int MODE>
__global__ __launch_bounds__(256, (BM==128)?3:2) void k_gemm2b(
    const char* __restrict__ A, const char* __restrict__ B,
    int K, int lda, int ldb, int ldc, int vnt, int ntreal,
    const float* __restrict__ rowdeq, const float* __restrict__ deqp,
    const float* __restrict__ resid, float* __restrict__ outF,
    u16* __restrict__ outB)
{
  constexpr int BN = 128;
  constexpr int MR = BM/32, NR = 4, MRH = MR/2;  // wave-tile (BM/2)x64
  constexpr int RA = BM/64, RB = 2;              // GLD16 rounds (256 threads)
  constexpr int ASZ = BM*64, BSZ = BN*64;
  constexpr int BUFSZ = ASZ + BSZ;               // 24KB / 16KB
  __shared__ __align__(16) char sm8[2*BUFSZ];

  const int tid = threadIdx.x;
  const int lane = tid & 63, wv = tid >> 6;   // 4 waves
  const int wr = wv >> 1, wc = wv & 1;        // 2x2 wave grid
  const int r = lane & 15, qq = lane >> 4;

  int mt, nt;
  const int lin = blockIdx.x;
  if constexpr (MODE == 3){
    // XCD-rectangle mapping; vnt % 8 == 0, dead virtual blocks exit
    const int xcd = lin & 7, i0 = lin >> 3;
    const int xcdw = vnt >> 3;
    const int ntl = i0 % xcdw; mt = i0 / xcdw;
    nt = xcd*xcdw + ntl;
    if (nt >= ntreal) return;
  } else {
    // chunked bijective XCD swizzle
    const int chunk = gridDim.x >> 3;
    const int swz = (lin & 7)*chunk + (lin >> 3);
    mt = swz / vnt; nt = swz - mt*vnt;
  }
  const long m0 = (long)mt*BM, n0 = (long)nt*BN;

  const char* __restrict__ gA = A + m0*lda;
  const char* __restrict__ gB = B + n0*ldb;

  // staging offsets: LDS linear slot c -> global group g = (c&3)^((row>>1)&3)
  int  soA[RA], soB[RB];
  long goA[RA], goB[RB];
#pragma unroll
  for (int u = 0; u < RA; u++){
    int c = u*256 + tid, row = c >> 2, g = (c & 3) ^ ((row>>1)&3);
    soA[u] = c*16; goA[u] = (long)row*lda + g*16;
  }
#pragma unroll
  for (int u = 0; u < RB; u++){
    int c = u*256 + tid, row = c >> 2, g = (c & 3) ^ ((row>>1)&3);
    soB[u] = c*16; goB[u] = (long)row*ldb + g*16;
  }
  const int gsw = (qq ^ ((r>>1)&3))*16;
  const int aoff0 = (wr*(BM/2) + r)*64 + gsw;
  const int boff0 = (wc*64 + r)*64 + gsw;

  const int NT = K >> 6;

  i32x4 acc[MR][NR];
#pragma unroll
  for (int i = 0; i < MR; i++)
#pragma unroll
    for (int j = 0; j < NR; j++) acc[i][j] = (i32x4){0,0,0,0};

  auto stA = [&](int tq){
    char* dst = sm8 + (tq&1)*BUFSZ;
    const char* src = gA + (long)tq*64;
#pragma unroll
    for (int u = 0; u < RA; u++) GLD16(src + goA[u], dst + soA[u]);
  };
  auto stB = [&](int tq){
    char* dst = sm8 + (tq&1)*BUFSZ + ASZ;
    const char* src = gB + (long)tq*64;
#pragma unroll
    for (int u = 0; u < RB; u++) GLD16(src + goB[u], dst + soB[u]);
  };

  // prologue: A0 B0 B1 in flight; wait A0,B0 landed (B1's RB=2 flying).
  stA(0); stB(0); stB(1);
  VMCNT(2);
  SBAR();

  for (int t = 0; t < NT; t++){
    const char* cA = sm8 + (t&1)*BUFSZ;
    const char* cB = cA + ASZ;
    i32x4 bF[NR];
    // ---- phase 0: m-half 0 ----
    {
      i32x4 aF[MRH];
#pragma unroll
      for (int i = 0; i < MRH; i++) aF[i] = *(const i32x4*)(cA + aoff0 + i*1024);
#pragma unroll
      for (int j = 0; j < NR; j++)  bF[j] = *(const i32x4*)(cB + boff0 + j*1024);
      if (t+1 < NT) stA(t+1);               // into buf^1: its A reads ended tile t-1
      SBAR();
      __builtin_amdgcn_s_setprio(1);
#pragma unroll
      for (int i = 0; i < MRH; i++)
#pragma unroll
        for (int j = 0; j < NR; j++)
          acc[i][j] = __builtin_amdgcn_mfma_i32_16x16x64_i8(aF[i], bF[j], acc[i][j], 0,0,0);
      __builtin_amdgcn_s_setprio(0);
      SBAR();
    }
    // ---- phase 1: m-half 1 (reuses bF) ----
    {
      i32x4 aF[MRH];
#pragma unroll
      for (int i = 0; i < MRH; i++) aF[i] = *(const i32x4*)(cA + aoff0 + (MRH+i)*1024);
      if (t+2 < NT) stB(t+2);               // into cur buf: B(cur) reads ended ph0
      SBAR();
      __builtin_amdgcn_s_setprio(1);
#pragma unroll
      for (int i = 0; i < MRH; i++)
#pragma unroll
        for (int j = 0; j < NR; j++)
          acc[MRH+i][j] = __builtin_amdgcn_mfma_i32_16x16x64_i8(aF[i], bF[j], acc[MRH+i][j], 0,0,0);
      __builtin_amdgcn_s_setprio(0);
      // boundary: t+1 landed, B(t+2) (=RB) stays in flight.
      if (t + 1 < NT){
        if (t + 2 < NT) VMCNT(2); else VMCNT(0);
      }
      SBAR();
    }
  }

  // epilogue
#pragma unroll
  for (int i = 0; i < MR; i++){
#pragma unroll
    for (int tt = 0; tt < 4; tt++){
      const long row = m0 + wr*(BM/2) + 16*i + 4*qq + tt;
      const float rdv = rowdeq[row];
      if constexpr (MODE == 3){
        const float dqg = deqp[0], dqu = deqp[1];
#pragma unroll
        for (int j = 0; j < NR; j += 2){
          const long col = n0 + wc*64 + 16*j + r;       // gate col
          float g = (float)acc[i][j][tt]   * rdv * dqg;
          float u = (float)acc[i][j+1][tt] * rdv * dqu;
          float hv = g * (1.0f/(1.0f + __expf(-g))) * u;
          const long hcol = (col >> 5)*16 + (col & 15); // original SwiGLU column
          outB[row*(long)ldc + hcol] = f2bf(hv);
        }
      } else {
#pragma unroll
        for (int j = 0; j < NR; j++){
          const long col = n0 + wc*64 + 16*j + r;
          float vv = (float)acc[i][j][tt];
          outF[row*(long)ldc + col] = vv*rdv*deqp[0] + resid[row*(long)ldc + col];
        }
      }
    }
  }
}

// ---------------- flash attention v4: in-place pipelined, swizzled LDS -----------
// Output now bf16 (halves O-traffic; consumer quantizes to i8 immediately).
__global__ __launch_bounds__(256) void k_attn(const u16* __restrict__ Y,
                                              const u16* __restrict__ VT,
                                              u16* __restrict__ O)
{
  __shared__ u16 Ks[64*128];     // [key][d], 16B group g stored at g^(key&7)
  __shared__ u16 VTs[128*64];    // [d][key], 16B group g stored at g^(d&7)
  __shared__ u16 Ps[64][72];     // P tile (wave-private rows, padded)

  const int pp = blockIdx.x;               // 0..15
  const int bh = blockIdx.y;
  const int b = bh >> 4, h = bh & 15, hk = h >> 2;
  const int tid = threadIdx.x;
  const int lane = tid & 63, wv = tid >> 6;
  const int r = lane & 15, qq = lane >> 4;
  const long rowbase = (long)b * SEQ;
  const u16* Kbase = Y + rowbase*QKV_N + 2048 + hk*128;
  const u16* Vbase = VT + ((long)(b*4+hk))*128*SEQ;

  for (int ph = 0; ph < 2; ph++){
    const int qt = ph ? pp : 31 - pp;
    const int q0 = qt * 64;

    bf16x8 qf[4];
#pragma unroll
    for (int kc = 0; kc < 4; kc++)
      qf[kc] = *(const bf16x8*)(Y + (rowbase + q0 + wv*16 + r)*QKV_N + h*128 + kc*32 + qq*8);

    // preload tile 0
#pragma unroll
    for (int rnd = 0; rnd < 4; rnd++){
      int c = rnd*256 + tid;
      int row = c >> 4, g = (c & 15) ^ (row & 7);
      GLD16(Kbase + ((long)(qt*0 + row))*QKV_N + g*8, (char*)Ks + c*16);
    }
#pragma unroll
    for (int rnd = 0; rnd < 4; rnd++){
      int c = rnd*256 + tid;
      int d = c >> 3, g = (c & 7) ^ (d & 7);
      GLD16(Vbase + (long)d*SEQ + g*8, (char*)VTs + c*16);
    }
    __syncthreads();

    f32x4 accO[8];
#pragma unroll
    for (int jn = 0; jn < 8; jn++) accO[jn] = (f32x4){0.f,0.f,0.f,0.f};
    float m_run[4] = {-INFINITY,-INFINITY,-INFINITY,-INFINITY};
    float l_run[4] = {0.f,0.f,0.f,0.f};

    for (int kt = 0; kt <= qt; kt++){
      // S = Q K^T
      float sv[4][4];
#pragma unroll
      for (int j = 0; j < 4; j++){
        f32x4 a = (f32x4){0.f,0.f,0.f,0.f};
#pragma unroll
        for (int kc = 0; kc < 4; kc++){
          bf16x8 kf = *(const bf16x8*)(Ks + (16*j + r)*128 + (((kc*4 + qq) ^ (r & 7)))*8);
          a = __builtin_amdgcn_mfma_f32_16x16x32_bf16(qf[kc], kf, a, 0, 0, 0);
        }
#pragma unroll
        for (int t = 0; t < 4; t++) sv[j][t] = a[t] * ATT_SCALE;
      }
      __syncthreads();                       // bar1: Ks free; drains V(kt) of prev iter
      if (kt < qt){
#pragma unroll
        for (int rnd = 0; rnd < 4; rnd++){
          int c = rnd*256 + tid;
          int row = c >> 4, g = (c & 15) ^ (row & 7);
          GLD16(Kbase + ((long)((kt+1)*64 + row))*QKV_N + g*8, (char*)Ks + c*16);
        }
      }
      if (kt == qt){
#pragma unroll
        for (int j = 0; j < 4; j++){
          int key = kt*64 + 16*j + r;
#pragma unroll
          for (int t = 0; t < 4; t++){
            int qr = q0 + wv*16 + 4*qq + t;
            if (key > qr) sv[j][t] = -INFINITY;
          }
        }
      }
      // online softmax per q-row
#pragma unroll
      for (int t = 0; t < 4; t++){
        float mm = fmaxf(fmaxf(sv[0][t],sv[1][t]), fmaxf(sv[2][t],sv[3][t]));
#pragma unroll
        for (int o = 8; o > 0; o >>= 1) mm = fmaxf(mm, __shfl_xor(mm, o));
        float mnew = fmaxf(m_run[t], mm);
        float alpha = __expf(m_run[t] - mnew);
        m_run[t] = mnew;
        float ps = 0.f;
#pragma unroll
        for (int j = 0; j < 4; j++){
          float p = __expf(sv[j][t] - mnew);
          ps += p;
          Ps[wv*16 + 4*qq + t][16*j + r] = f2bf(p);
        }
#pragma unroll
        for (int o = 8; o > 0; o >>= 1) ps += __shfl_xor(ps, o);
        l_run[t] = l_run[t]*alpha + ps;
#pragma unroll
        for (int jn = 0; jn < 8; jn++) accO[jn][t] *= alpha;
      }
      // O += P V
#pragma unroll
      for (int kc = 0; kc < 2; kc++){
        bf16x8 pf = *(const bf16x8*)&Ps[wv*16 + r][kc*32 + qq*8];
#pragma unroll
        for (int jn = 0; jn < 8; jn++){
          bf16x8 vf = *(const bf16x8*)(VTs + (16*jn + r)*64 + (((kc*4 + qq) ^ (r & 7)))*8);
          accO[jn] = __builtin_amdgcn_mfma_f32_16x16x32_bf16(pf, vf, accO[jn], 0, 0, 0);
        }
      }
      __syncthreads();                       // bar2: VTs free; drains K(kt+1)
      if (kt < qt){
#pragma unroll
        for (int rnd = 0; rnd < 4; rnd++){
          int c = rnd*256 + tid;
          int d = c >> 3, g = (c & 7) ^ (d & 7);
          GLD16(Vbase + (long)d*SEQ + (kt+1)*64 + g*8, (char*)VTs + c*16);
        }
      }
    }
    float inv[4];
#pragma unroll
    for (int t = 0; t < 4; t++) inv[t] = 1.0f / l_run[t];
#pragma unroll
    for (int jn = 0; jn < 8; jn++){
#pragma unroll
      for (int t = 0; t < 4; t++){
        long row = rowbase + q0 + wv*16 + 4*qq + t;
        O[row*DIMC + h*128 + 16*jn + r] = f2bf(accO[jn][t]*inv[t]);
      }
    }
    __syncthreads();   // protect Ks/VTs before next phase preload
  }
}

// ---------------- h bf16 [4096][5504] -> act_quant i8 ----------------
__global__ __launch_bounds__(256) void k_hquant(const u16* __restrict__ hbuf,
                                                char* __restrict__ qout,
                                                float* __restrict__ rowdeq){
  const int row = blockIdx.x, tid = threadIdx.x;
  const u16* base = hbuf + (long)row * MLP_P;
  float h[24];
  float amax = 0.f;
#pragma unroll
  for (int it = 0; it < 3; it++){
    int chunk = it*256 + tid;
    if (chunk < 688){
      int j0 = chunk*8;
      int4 h4 = *(const int4*)(base + j0);
      const u16* hp = (const u16*)&h4;
#pragma unroll
      for (int e = 0; e < 8; e++){
        float hv = bf2f(hp[e]);
        h[it*8+e] = hv;
        amax = fmaxf(amax, fabsf(hv));
      }
    } else {
#pragma unroll
      for (int e = 0; e < 8; e++) h[it*8+e] = 0.f;
    }
  }
  amax = waveRedMax(amax);
  __shared__ float sm[4];
  int lane = tid & 63, wv = tid >> 6;
  if (lane == 0) sm[wv] = amax;
  __syncthreads();
  float gmax = fmaxf(fmaxf(sm[0],sm[1]), fmaxf(sm[2],sm[3]));
  float sc = 127.0f / fmaxf(gmax, 1e-5f);
#pragma unroll
  for (int it = 0; it < 3; it++){
    int chunk = it*256 + tid;
    if (chunk < 688){
      int j0 = chunk*8;
      int2 o;
      char* oc = (char*)&o;
#pragma unroll
      for (int e = 0; e < 8; e++)
        oc[e] = (char)(int)fminf(fmaxf(rintf(h[it*8+e]*sc), -128.f), 127.f);
      *(int2*)(qout + (long)row*MLP_P + j0) = o;
    }
  }
  if (tid == 0) rowdeq[row] = 1.0f/sc;
}

extern "C" void kernel_launch(void* const* d_in, const int* in_sizes, int n_in,
                              void* d_out, int out_size, void* d_ws, size_t ws_size,
                              hipStream_t stream)
{
  (void)in_sizes; (void)n_in; (void)out_size; (void)ws_size;
  const float* x   = (const float*)d_in[0];
  const int*   pos = (const int*)d_in[1];
  const float* n1w = (const float*)d_in[2];
  const float* qw  = (const float*)d_in[3];
  const float* qb  = (const float*)d_in[4];
  const float* kw  = (const float*)d_in[5];
  const float* kb  = (const float*)d_in[6];
  const float* vw  = (const float*)d_in[7];
  const float* vb  = (const float*)d_in[8];
  const float* ow  = (const float*)d_in[9];
  const float* n2w = (const float*)d_in[10];
  const float* gw  = (const float*)d_in[11];
  const float* uw  = (const float*)d_in[12];
  const float* dw  = (const float*)d_in[13];
  float* out = (float*)d_out;
  char* ws = (char*)d_ws;

  // one-time: allow >64KB dynamic LDS for the k_gemm8 QKV instantiation
  static int attr_done = 0;
  if (!attr_done){
    hipFuncSetAttribute(reinterpret_cast<const void*>(k_gemm8<256,128,4,2,0>),
                        hipFuncAttributeMaxDynamicSharedMemorySize, 98304);
    attr_done = 1;
  }

  // workspace layout (all offsets multiple of 256)
  float* sc   = (float*)ws;                 // [0..6] sums, [8..14] deq
  char* Wqkv  = ws + 256;                   // [3072][2048] i8   (6.29 MB)
  char* Wo    = ws + 6291712;               // [2048][2048] i8   (4.19 MB)
  char* Wgu   = ws + 10486016;              // [11008][2048] i8 interleaved (22.5 MB)
  char* Wd    = ws + 33030400;              // [2048][5504] i8   (11.3 MB)
  char* actq  = ws + 44302592;              // [4096][2048] i8   (8.39 MB)
  char* swq   = ws + 52691200;              // [4096][5504] i8   (22.5 MB)
  float* rd   = (float*)(ws + 75235584);    // [4096] fp32
  char* xreg  = ws + 75252224;              // overlay region (90.2 MB)
  u16* yqkv   = (u16*)xreg;                 // [4096][3072] bf16 (25.2 MB)
  u16* attnb  = (u16*)(xreg + 25165824);    // [4096][2048] bf16 (16.8 MB)
  u16* vT     = (u16*)(xreg + 58720256);    // [8][128][2048] bf16 (8.4 MB)
  u16* hbuf   = (u16*)xreg;                 // [4096][5504] bf16 (45.1 MB, after attention)

  // ---- weight scales + ternary i8 quant (fused dispatches) ----
  hipMemsetAsync(sc, 0, 64, stream);
  hipMemsetAsync(Wgu, 0, 11008l*2048, stream);   // zero pads for interleaved layout
  k_abssum7<<<dim3(512,7),256,0,stream>>>((const float4*)qw, (const float4*)kw,
                                          (const float4*)vw, (const float4*)ow,
                                          (const float4*)gw, (const float4*)uw,
                                          (const float4*)dw, sc);
  k_finalize<<<1,64,0,stream>>>(sc);
  k_wquant6<<<dim3(512,6),256,0,stream>>>((const float4*)qw, (const float4*)kw,
                                          (const float4*)vw, (const float4*)ow,
                                          (const float4*)gw, (const float4*)uw,
                                          (u32*)Wqkv, (u32*)(Wqkv + 2048l*2048),
                                          (u32*)(Wqkv + 2560l*2048), (u32*)Wo,
                                          (u32*)Wgu, sc);
  k_wquant_down<<<11008,256,0,stream>>>(dw, (u32*)Wd, sc+14);

  // ---- attention half ----
  k_rmsq<<<4096,256,0,stream>>>(x, n1w, actq, rd, 1);
  k_gemm8<256,128,4,2,0><<<384,512,98304,stream>>>(actq, Wqkv, 2048, 2048, 2048, 3072, 24,
                                          rd, sc+8, qb, kb, vb, nullptr, nullptr, yqkv);
  k_ropevt2<<<5120,256,0,stream>>>(yqkv, pos, vT);
  k_attn<<<dim3(16,32),256,0,stream>>>(yqkv, vT, attnb);
  k_quantb<<<4096,256,0,stream>>>(attnb, actq, rd);
  k_gemm2b<128,1><<<512,256,0,stream>>>(actq, Wo, 2048, 2048, 2048, 2048, 16, 16,
                                        rd, sc+11, x, out, nullptr);

  // ---- MLP half (x1 lives in d_out) ----
  k_rmsq<<<4096,256,0,stream>>>(out, n2w, actq, rd, 1);
  k_gemm2b<256,3><<<1408,256,0,stream>>>(actq, Wgu, 2048, 2048, 2048, MLP_P, 88, 86,
                                         rd, sc+12, nullptr, nullptr, hbuf);
  k_hquant<<<4096,256,0,stream>>>(hbuf, swq, rd);
  k_gemm2b<128,1><<<512,256,0,stream>>>(swq, Wd, 5504, 5504, 5504, 2048, 16, 16,
                                        rd, sc+14, out, out, nullptr);
}

// Round 9
// 654.563 us; speedup vs baseline: 1.0595x; 1.0289x over previous
//
#include <hip/hip_runtime.h>

typedef unsigned short u16;
typedef unsigned int   u32;
typedef unsigned char  u8;

using bf16x8 = __attribute__((ext_vector_type(8))) short;
using f32x4  = __attribute__((ext_vector_type(4))) float;
using i32x4  = __attribute__((ext_vector_type(4))) int;

#define SEQ    2048
#define DIMC   2048
#define TOK    4096
#define QKV_N  3072
#define GU_N   11008
#define MLP_P  5504
#define MLP_R  5461
#define ATT_SCALE 0.08838834764831845f

__device__ __forceinline__ float bf2f(u16 v){ return __uint_as_float(((u32)v) << 16); }
__device__ __forceinline__ u16 f2bf(float f){
  u32 x = __float_as_uint(f);
  u32 r = (x + 0x7fffu + ((x >> 16) & 1u)) >> 16;
  return (u16)r;
}

__device__ __forceinline__ float waveRedSum(float v){
#pragma unroll
  for (int o = 32; o > 0; o >>= 1) v += __shfl_xor(v, o);
  return v;
}
__device__ __forceinline__ float waveRedMax(float v){
#pragma unroll
  for (int o = 32; o > 0; o >>= 1) v = fmaxf(v, __shfl_xor(v, o));
  return v;
}

// async global->LDS, 16B per lane. LDS dest is wave-uniform base + lane*16.
#define GLD16(gp, lp) __builtin_amdgcn_global_load_lds( \
    (__attribute__((address_space(1))) void*)(gp), \
    (__attribute__((address_space(3))) void*)(lp), 16, 0, 0)

#define FENCE() asm volatile("" ::: "memory")
#define SBAR()  do{ FENCE(); __builtin_amdgcn_s_barrier(); FENCE(); }while(0)
#define VMCNT(n) asm volatile("s_waitcnt vmcnt(" #n ")" ::: "memory")

// inline dequant scale from raw abs-sum (replaces the old k_finalize dispatch)
__device__ __forceinline__ float deq_of(float sum, float cnt){
  return fmaxf(sum/cnt, 1e-5f);
}

// ---------------- fused weight abs-sums (7 regions in one dispatch) ----------------
__global__ __launch_bounds__(256) void k_abssum7(
    const float4* __restrict__ w0, const float4* __restrict__ w1,
    const float4* __restrict__ w2, const float4* __restrict__ w3,
    const float4* __restrict__ w4, const float4* __restrict__ w5,
    const float4* __restrict__ w6, float* __restrict__ sc){
  const int rg = blockIdx.y;
  const float4* w = rg==0?w0: rg==1?w1: rg==2?w2: rg==3?w3: rg==4?w4: rg==5?w5: w6;
  const int n4 = (rg==0||rg==3) ? 1048576 : (rg<4 ? 262144 : 2796032);
  float s = 0.f;
  for (int i = blockIdx.x*256 + threadIdx.x; i < n4; i += gridDim.x*256){
    float4 v = w[i];
    s += fabsf(v.x) + fabsf(v.y) + fabsf(v.z) + fabsf(v.w);
  }
  s = waveRedSum(s);
  __shared__ float sm[4];
  int lane = threadIdx.x & 63, wv = threadIdx.x >> 6;
  if (lane == 0) sm[wv] = s;
  __syncthreads();
  if (threadIdx.x == 0) atomicAdd(sc + rg, sm[0]+sm[1]+sm[2]+sm[3]);
}

// ---------------- fused ternary weight quant (6 regions) -> packed i8 ----------------
// Regions 4 (gate) and 5 (up) are written INTERLEAVED into Wgu:
//   gate row j -> Wgu row 32*(j>>4) + (j&15)
//   up   row j -> Wgu row 32*(j>>4) + 16 + (j&15)
// Gate/up iterate the PADDED row range [0,5504) and write zeros for j >= 5461 —
// the interleave map is bijective onto [0,11008), so every Wgu row is written
// and no separate memset dispatch is needed. deq computed inline from raw sums.
__global__ __launch_bounds__(256) void k_wquant6(
    const float4* __restrict__ w0, const float4* __restrict__ w1,
    const float4* __restrict__ w2, const float4* __restrict__ w3,
    const float4* __restrict__ w4, const float4* __restrict__ w5,
    u32* __restrict__ d0, u32* __restrict__ d1, u32* __restrict__ d2,
    u32* __restrict__ d3, u32* __restrict__ dgu,
    const float* __restrict__ sc){
  const int rg = blockIdx.y;
  const float4* src = rg==0?w0: rg==1?w1: rg==2?w2: rg==3?w3: rg==4?w4: w5;
  const int n4 = (rg==0||rg==3) ? 1048576 : (rg<4 ? 262144 : 2818048);  // 5504*512 padded
  const float cnt = (rg==0||rg==3) ? 4194304.f : (rg<4 ? 1048576.f : 11184128.f);
  float ws = 1.0f / deq_of(sc[rg], cnt);
  for (int i = blockIdx.x*256 + threadIdx.x; i < n4; i += gridDim.x*256){
    u32 pk = 0;
    int row = i >> 9;
    if (rg < 4 || row < MLP_R){
      float4 v = src[i];
      int c0 = (int)fminf(fmaxf(rintf(v.x*ws), -1.f), 1.f);
      int c1 = (int)fminf(fmaxf(rintf(v.y*ws), -1.f), 1.f);
      int c2 = (int)fminf(fmaxf(rintf(v.z*ws), -1.f), 1.f);
      int c3 = (int)fminf(fmaxf(rintf(v.w*ws), -1.f), 1.f);
      pk = (u32)(u8)c0 | ((u32)(u8)c1 << 8) | ((u32)(u8)c2 << 16) | ((u32)(u8)c3 << 24);
    }
    if (rg < 4){
      u32* dst = rg==0?d0: rg==1?d1: rg==2?d2: d3;
      dst[i] = pk;
    } else {
      int col = i & 511;                          // 512 u32 per 2048-col row
      int rI = 32*(row>>4) + (row&15) + ((rg==5)?16:0);
      dgu[(long)rI*512 + col] = pk;
    }
  }
}

// down_w [2048][5461] fp32 -> [2048][5504] i8 padded with zeros (inline deq from sc[6])
__global__ __launch_bounds__(256) void k_wquant_down(const float* __restrict__ src,
                                                     u32* __restrict__ dst,
                                                     const float* __restrict__ sc6){
  int i = blockIdx.x*256 + threadIdx.x;
  const int total = 2048*(MLP_P/4);
  if (i >= total) return;
  float ws = 1.0f / deq_of(sc6[0], 11184128.f);
  int r = i / (MLP_P/4);
  int c4 = (i - r*(MLP_P/4))*4;
  u32 o = 0;
#pragma unroll
  for (int e = 0; e < 4; e++){
    int c = c4 + e;
    int t = 0;
    if (c < MLP_R) t = (int)fminf(fmaxf(rintf(src[(long)r*MLP_R + c]*ws), -1.f), 1.f);
    o |= (u32)(u8)t << (8*e);
  }
  dst[i] = o;
}

// ---------------- rmsnorm (optional) + act_quant over 2048 fp32 -> i8 ----------------
__global__ __launch_bounds__(256) void k_rmsq(const float* __restrict__ in,
                                              const float* __restrict__ nw,
                                              char* __restrict__ outq,
                                              float* __restrict__ rowdeq, int do_norm){
  const int row = blockIdx.x, tid = threadIdx.x;
  const float* xp = in + (long)row * DIMC + tid*8;
  float v[8];
  float4 a0 = *(const float4*)xp;
  float4 a1 = *(const float4*)(xp + 4);
  v[0]=a0.x; v[1]=a0.y; v[2]=a0.z; v[3]=a0.w;
  v[4]=a1.x; v[5]=a1.y; v[6]=a1.z; v[7]=a1.w;
  float ss = 0.f;
#pragma unroll
  for (int j = 0; j < 8; j++) ss += v[j]*v[j];
  __shared__ float sm[8];
  int lane = tid & 63, wv = tid >> 6;
  ss = waveRedSum(ss);
  if (lane == 0) sm[wv] = ss;
  __syncthreads();
  float h[8];
  float amax = 0.f;
  if (do_norm){
    float tot = sm[0]+sm[1]+sm[2]+sm[3];
    float rms = rsqrtf(tot * (1.0f/DIMC) + 1.1920929e-07f);
    float4 w0 = *(const float4*)(nw + tid*8);
    float4 w1 = *(const float4*)(nw + tid*8 + 4);
    float wr8[8] = {w0.x,w0.y,w0.z,w0.w,w1.x,w1.y,w1.z,w1.w};
#pragma unroll
    for (int j = 0; j < 8; j++){ h[j] = v[j]*rms*wr8[j]; amax = fmaxf(amax, fabsf(h[j])); }
  } else {
#pragma unroll
    for (int j = 0; j < 8; j++){ h[j] = v[j]; amax = fmaxf(amax, fabsf(h[j])); }
  }
  amax = waveRedMax(amax);
  if (lane == 0) sm[4+wv] = amax;
  __syncthreads();
  float gmax = fmaxf(fmaxf(sm[4],sm[5]), fmaxf(sm[6],sm[7]));
  float sc = 127.0f / fmaxf(gmax, 1e-5f);
  int2 o;
  char* oc = (char*)&o;
#pragma unroll
  for (int j = 0; j < 8; j++)
    oc[j] = (char)(int)fminf(fmaxf(rintf(h[j]*sc), -128.f), 127.f);
  *(int2*)(outq + (long)row*DIMC + tid*8) = o;
  if (tid == 0) rowdeq[row] = 1.0f / sc;
}

// ---------------- act_quant over 2048 bf16 -> i8 (attention output) ----------------
__global__ __launch_bounds__(256) void k_quantb(const u16* __restrict__ in,
                                                char* __restrict__ outq,
                                                float* __restrict__ rowdeq){
  const int row = blockIdx.x, tid = threadIdx.x;
  int4 a = *(const int4*)(in + (long)row*DIMC + tid*8);
  const u16* ap = (const u16*)&a;
  float v[8];
  float amax = 0.f;
#pragma unroll
  for (int j = 0; j < 8; j++){ v[j] = bf2f(ap[j]); amax = fmaxf(amax, fabsf(v[j])); }
  amax = waveRedMax(amax);
  __shared__ float sm[4];
  int lane = tid & 63, wv = tid >> 6;
  if (lane == 0) sm[wv] = amax;
  __syncthreads();
  float gmax = fmaxf(fmaxf(sm[0],sm[1]), fmaxf(sm[2],sm[3]));
  float sc = 127.0f / fmaxf(gmax, 1e-5f);
  int2 o;
  char* oc = (char*)&o;
#pragma unroll
  for (int j = 0; j < 8; j++)
    oc[j] = (char)(int)fminf(fmaxf(rintf(v[j]*sc), -128.f), 127.f);
  *(int2*)(outq + (long)row*DIMC + tid*8) = o;
  if (tid == 0) rowdeq[row] = 1.0f / sc;
}

// ---------------- RoPE v2 (per-row LDS sincos table) + V transpose ----------------
__global__ __launch_bounds__(256) void k_ropevt2(u16* __restrict__ y,
                                                 const int* __restrict__ pos_ids,
                                                 u16* __restrict__ VT){
  if (blockIdx.x < 4096){
    const int m = blockIdx.x, tid = threadIdx.x;
    __shared__ float cs[64], sn[64];
    if (tid < 64){
      float pos = (float)pos_ids[m];
      float inv = expf((float)tid * -0.14391156831212787f);  // 10000^(-tid/64)
      float s, c;
      sincosf(pos * inv, &s, &c);
      cs[tid] = c; sn[tid] = s;
    }
    __syncthreads();
    u32* row = (u32*)(y + (long)m*QKV_N);
#pragma unroll
    for (int it = 0; it < 5; it++){
      int p = it*256 + tid;          // pair index < 1280 (cols [0,2560))
      int i = p & 63;
      u32 both = row[p];
      float x0 = bf2f((u16)(both & 0xffffu));
      float x1 = bf2f((u16)(both >> 16));
      float c = cs[i], s = sn[i];
      u16 o0 = f2bf(x0*c - x1*s);
      u16 o1 = f2bf(x1*c + x0*s);
      row[p] = (u32)o0 | ((u32)o1 << 16);
    }
  } else {
    int idx = (int)(blockIdx.x - 4096)*256 + threadIdx.x;  // < 262144
    int d  = idx & 127;
    int hk = (idx >> 7) & 3;
    int b  = (idx >> 9) & 1;
    int tg = idx >> 10;                       // 0..255
    int tok0 = tg*8;
    const u16* src = y + ((long)b*SEQ + tok0)*QKV_N + 2560 + hk*128 + d;
    u16 tmp[8];
#pragma unroll
    for (int e = 0; e < 8; e++) tmp[e] = src[(long)e*QKV_N];
    *(int4*)(VT + (((long)(b*4+hk))*128 + d)*SEQ + tok0) = *(int4*)tmp;
  }
}

// ---------------- GEMM 2b (R2/R6-proven sync structure): BMx128, 4 waves ----------
// BM=256 (MODE 3, GU+fused SwiGLU): 48KB LDS -> 2 blocks/CU, XCD-rect mapping.
// BM=128 (MODE 0 QKV / MODE 1 O,Down): 32KB LDS, 64-AGPR acc -> 3 blocks/CU
// anti-phased, chunked swizzle. Identical vmcnt literals (boundary outstanding = 2).
// Dequant scales computed inline from raw abs-sums (sums/cnt, clipped at 1e-5).
template<int BM, int MODE>
__global__ __launch_bounds__(256, (BM==128)?3:2) void k_gemm2b(
    const char* __restrict__ A, const char* __restrict__ B,
    int K, int lda, int ldb, int ldc, int vnt, int ntreal,
    const float* __restrict__ rowdeq, const float* __restrict__ sums, float cnt,
    const float* __restrict__ bq, const float* __restrict__ bk, const float* __restrict__ bv,
    const float* __restrict__ resid, float* __restrict__ outF,
    u16* __restrict__ outB)
{
  constexpr int BN = 128;
  constexpr int MR = BM/32, NR = 4, MRH = MR/2;  // wave-tile (BM/2)x64
  constexpr int RA = BM/64, RB = 2;              // GLD16 rounds (256 threads)
  constexpr int ASZ = BM*64, BSZ = BN*64;
  constexpr int BUFSZ = ASZ + BSZ;               // 24KB / 16KB
  __shared__ __align__(16) char sm8[2*BUFSZ];

  const int tid = threadIdx.x;
  const int lane = tid & 63, wv = tid >> 6;   // 4 waves
  const int wr = wv >> 1, wc = wv & 1;        // 2x2 wave grid
  const int r = lane & 15, qq = lane >> 4;

  int mt, nt;
  const int lin = blockIdx.x;
  if constexpr (MODE == 3){
    // XCD-rectangle mapping; vnt % 8 == 0, dead virtual blocks exit
    const int xcd = lin & 7, i0 = lin >> 3;
    const int xcdw = vnt >> 3;
    const int ntl = i0 % xcdw; mt = i0 / xcdw;
    nt = xcd*xcdw + ntl;
    if (nt >= ntreal) return;
  } else {
    // chunked bijective XCD swizzle
    const int chunk = gridDim.x >> 3;
    const int swz = (lin & 7)*chunk + (lin >> 3);
    mt = swz / vnt; nt = swz - mt*vnt;
  }
  const long m0 = (long)mt*BM, n0 = (long)nt*BN;

  const char* __restrict__ gA = A + m0*lda;
  const char* __restrict__ gB = B + n0*ldb;

  // staging offsets: LDS linear slot c -> global group g = (c&3)^((row>>1)&3)
  int  soA[RA], soB[RB];
  long goA[RA], goB[RB];
#pragma unroll
  for (int u = 0; u < RA; u++){
    int c = u*256 + tid, row = c >> 2, g = (c & 3) ^ ((row>>1)&3);
    soA[u] = c*16; goA[u] = (long)row*lda + g*16;
  }
#pragma unroll
  for (int u = 0; u < RB; u++){
    int c = u*256 + tid, row = c >> 2, g = (c & 3) ^ ((row>>1)&3);
    soB[u] = c*16; goB[u] = (long)row*ldb + g*16;
  }
  const int gsw = (qq ^ ((r>>1)&3))*16;
  const int aoff0 = (wr*(BM/2) + r)*64 + gsw;
  const int boff0 = (wc*64 + r)*64 + gsw;

  const int NT = K >> 6;

  i32x4 acc[MR][NR];
#pragma unroll
  for (int i = 0; i < MR; i++)
#pragma unroll
    for (int j = 0; j < NR; j++) acc[i][j] = (i32x4){0,0,0,0};

  auto stA = [&](int tq){
    char* dst = sm8 + (tq&1)*BUFSZ;
    const char* src = gA + (long)tq*64;
#pragma unroll
    for (int u = 0; u < RA; u++) GLD16(src + goA[u], dst + soA[u]);
  };
  auto stB = [&](int tq){
    char* dst = sm8 + (tq&1)*BUFSZ + ASZ;
    const char* src = gB + (long)tq*64;
#pragma unroll
    for (int u = 0; u < RB; u++) GLD16(src + goB[u], dst + soB[u]);
  };

  // prologue: A0 B0 B1 in flight; wait A0,B0 landed (B1's RB=2 flying).
  stA(0); stB(0); stB(1);
  VMCNT(2);
  SBAR();

  for (int t = 0; t < NT; t++){
    const char* cA = sm8 + (t&1)*BUFSZ;
    const char* cB = cA + ASZ;
    i32x4 bF[NR];
    // ---- phase 0: m-half 0 ----
    {
      i32x4 aF[MRH];
#pragma unroll
      for (int i = 0; i < MRH; i++) aF[i] = *(const i32x4*)(cA + aoff0 + i*1024);
#pragma unroll
      for (int j = 0; j < NR; j++)  bF[j] = *(const i32x4*)(cB + boff0 + j*1024);
      if (t+1 < NT) stA(t+1);               // into buf^1: its A reads ended tile t-1
      SBAR();
      __builtin_amdgcn_s_setprio(1);
#pragma unroll
      for (int i = 0; i < MRH; i++)
#pragma unroll
        for (int j = 0; j < NR; j++)
          acc[i][j] = __builtin_amdgcn_mfma_i32_16x16x64_i8(aF[i], bF[j], acc[i][j], 0,0,0);
      __builtin_amdgcn_s_setprio(0);
      SBAR();
    }
    // ---- phase 1: m-half 1 (reuses bF) ----
    {
      i32x4 aF[MRH];
#pragma unroll
      for (int i = 0; i < MRH; i++) aF[i] = *(const i32x4*)(cA + aoff0 + (MRH+i)*1024);
      if (t+2 < NT) stB(t+2);               // into cur buf: B(cur) reads ended ph0
      SBAR();
      __builtin_amdgcn_s_setprio(1);
#pragma unroll
      for (int i = 0; i < MRH; i++)
#pragma unroll
        for (int j = 0; j < NR; j++)
          acc[MRH+i][j] = __builtin_amdgcn_mfma_i32_16x16x64_i8(aF[i], bF[j], acc[MRH+i][j], 0,0,0);
      __builtin_amdgcn_s_setprio(0);
      // boundary: t+1 landed, B(t+2) (=RB) stays in flight.
      if (t + 1 < NT){
        if (t + 2 < NT) VMCNT(2); else VMCNT(0);
      }
      SBAR();
    }
  }

  // epilogue
#pragma unroll
  for (int i = 0; i < MR; i++){
#pragma unroll
    for (int tt = 0; tt < 4; tt++){
      const long row = m0 + wr*(BM/2) + 16*i + 4*qq + tt;
      const float rdv = rowdeq[row];
      if constexpr (MODE == 0){
#pragma unroll
        for (int j = 0; j < NR; j++){
          const long col = n0 + wc*64 + 16*j + r;
          int sec = (col >= 2048) + (col >= 2560);
          float cn = (sec == 0) ? 4194304.f : 1048576.f;
          float dq = deq_of(sums[sec], cn);
          float bias = (sec == 0) ? bq[col] : (sec == 1) ? bk[col-2048] : bv[col-2560];
          float vv = (float)acc[i][j][tt];
          outB[row*(long)ldc + col] = f2bf(vv*rdv*dq + bias);
        }
      } else if constexpr (MODE == 3){
        const float dqg = deq_of(sums[0], 11184128.f);
        const float dqu = deq_of(sums[1], 11184128.f);
#pragma unroll
        for (int j = 0; j < NR; j += 2){
          const long col = n0 + wc*64 + 16*j + r;       // gate col
          float g = (float)acc[i][j][tt]   * rdv * dqg;
          float u = (float)acc[i][j+1][tt] * rdv * dqu;
          float hv = g * (1.0f/(1.0f + __expf(-g))) * u;
          const long hcol = (col >> 5)*16 + (col & 15); // original SwiGLU column
          outB[row*(long)ldc + hcol] = f2bf(hv);
        }
      } else {
        const float deq = deq_of(sums[0], cnt);
#pragma unroll
        for (int j = 0; j < NR; j++){
          const long col = n0 + wc*64 + 16*j + r;
          float vv = (float)acc[i][j][tt];
          outF[row*(long)ldc + col] = vv*rdv*deq + resid[row*(long)ldc + col];
        }
      }
    }
  }
}

// ---------------- flash attention v4: in-place pipelined, swizzled LDS -----------
// Output bf16 (halves O-traffic; consumer quantizes to i8 immediately).
__global__ __launch_bounds__(256) void k_attn(const u16* __restrict__ Y,
                                              const u16* __restrict__ VT,
                                              u16* __restrict__ O)
{
  __shared__ u16 Ks[64*128];     // [key][d], 16B group g stored at g^(key&7)
  __shared__ u16 VTs[128*64];    // [d][key], 16B group g stored at g^(d&7)
  __shared__ u16 Ps[64][72];     // P tile (wave-private rows, padded)

  const int pp = blockIdx.x;               // 0..15
  const int bh = blockIdx.y;
  const int b = bh >> 4, h = bh & 15, hk = h >> 2;
  const int tid = threadIdx.x;
  const int lane = tid & 63, wv = tid >> 6;
  const int r = lane & 15, qq = lane >> 4;
  const long rowbase = (long)b * SEQ;
  const u16* Kbase = Y + rowbase*QKV_N + 2048 + hk*128;
  const u16* Vbase = VT + ((long)(b*4+hk))*128*SEQ;

  for (int ph = 0; ph < 2; ph++){
    const int qt = ph ? pp : 31 - pp;
    const int q0 = qt * 64;

    bf16x8 qf[4];
#pragma unroll
    for (int kc = 0; kc < 4; kc++)
      qf[kc] = *(const bf16x8*)(Y + (rowbase + q0 + wv*16 + r)*QKV_N + h*128 + kc*32 + qq*8);

    // preload tile 0
#pragma unroll
    for (int rnd = 0; rnd < 4; rnd++){
      int c = rnd*256 + tid;
      int row = c >> 4, g = (c & 15) ^ (row & 7);
      GLD16(Kbase + ((long)(qt*0 + row))*QKV_N + g*8, (char*)Ks + c*16);
    }
#pragma unroll
    for (int rnd = 0; rnd < 4; rnd++){
      int c = rnd*256 + tid;
      int d = c >> 3, g = (c & 7) ^ (d & 7);
      GLD16(Vbase + (long)d*SEQ + g*8, (char*)VTs + c*16);
    }
    __syncthreads();

    f32x4 accO[8];
#pragma unroll
    for (int jn = 0; jn < 8; jn++) accO[jn] = (f32x4){0.f,0.f,0.f,0.f};
    float m_run[4] = {-INFINITY,-INFINITY,-INFINITY,-INFINITY};
    float l_run[4] = {0.f,0.f,0.f,0.f};

    for (int kt = 0; kt <= qt; kt++){
      // S = Q K^T
      float sv[4][4];
#pragma unroll
      for (int j = 0; j < 4; j++){
        f32x4 a = (f32x4){0.f,0.f,0.f,0.f};
#pragma unroll
        for (int kc = 0; kc < 4; kc++){
          bf16x8 kf = *(const bf16x8*)(Ks + (16*j + r)*128 + (((kc*4 + qq) ^ (r & 7)))*8);
          a = __builtin_amdgcn_mfma_f32_16x16x32_bf16(qf[kc], kf, a, 0, 0, 0);
        }
#pragma unroll
        for (int t = 0; t < 4; t++) sv[j][t] = a[t] * ATT_SCALE;
      }
      __syncthreads();                       // bar1: Ks free; drains V(kt) of prev iter
      if (kt < qt){
#pragma unroll
        for (int rnd = 0; rnd < 4; rnd++){
          int c = rnd*256 + tid;
          int row = c >> 4, g = (c & 15) ^ (row & 7);
          GLD16(Kbase + ((long)((kt+1)*64 + row))*QKV_N + g*8, (char*)Ks + c*16);
        }
      }
      if (kt == qt){
#pragma unroll
        for (int j = 0; j < 4; j++){
          int key = kt*64 + 16*j + r;
#pragma unroll
          for (int t = 0; t < 4; t++){
            int qr = q0 + wv*16 + 4*qq + t;
            if (key > qr) sv[j][t] = -INFINITY;
          }
        }
      }
      // online softmax per q-row
#pragma unroll
      for (int t = 0; t < 4; t++){
        float mm = fmaxf(fmaxf(sv[0][t],sv[1][t]), fmaxf(sv[2][t],sv[3][t]));
#pragma unroll
        for (int o = 8; o > 0; o >>= 1) mm = fmaxf(mm, __shfl_xor(mm, o));
        float mnew = fmaxf(m_run[t], mm);
        float alpha = __expf(m_run[t] - mnew);
        m_run[t] = mnew;
        float ps = 0.f;
#pragma unroll
        for (int j = 0; j < 4; j++){
          float p = __expf(sv[j][t] - mnew);
          ps += p;
          Ps[wv*16 + 4*qq + t][16*j + r] = f2bf(p);
        }
#pragma unroll
        for (int o = 8; o > 0; o >>= 1) ps += __shfl_xor(ps, o);
        l_run[t] = l_run[t]*alpha + ps;
#pragma unroll
        for (int jn = 0; jn < 8; jn++) accO[jn][t] *= alpha;
      }
      // O += P V
#pragma unroll
      for (int kc = 0; kc < 2; kc++){
        bf16x8 pf = *(const bf16x8*)&Ps[wv*16 + r][kc*32 + qq*8];
#pragma unroll
        for (int jn = 0; jn < 8; jn++){
          bf16x8 vf = *(const bf16x8*)(VTs + (16*jn + r)*64 + (((kc*4 + qq) ^ (r & 7)))*8);
          accO[jn] = __builtin_amdgcn_mfma_f32_16x16x32_bf16(pf, vf, accO[jn], 0, 0, 0);
        }
      }
      __syncthreads();                       // bar2: VTs free; drains K(kt+1)
      if (kt < qt){
#pragma unroll
        for (int rnd = 0; rnd < 4; rnd++){
          int c = rnd*256 + tid;
          int d = c >> 3, g = (c & 7) ^ (d & 7);
          GLD16(Vbase + (long)d*SEQ + (kt+1)*64 + g*8, (char*)VTs + c*16);
        }
      }
    }
    float inv[4];
#pragma unroll
    for (int t = 0; t < 4; t++) inv[t] = 1.0f / l_run[t];
#pragma unroll
    for (int jn = 0; jn < 8; jn++){
#pragma unroll
      for (int t = 0; t < 4; t++){
        long row = rowbase + q0 + wv*16 + 4*qq + t;
        O[row*DIMC + h*128 + 16*jn + r] = f2bf(accO[jn][t]*inv[t]);
      }
    }
    __syncthreads();   // protect Ks/VTs before next phase preload
  }
}

// ---------------- h bf16 [4096][5504] -> act_quant i8 ----------------
__global__ __launch_bounds__(256) void k_hquant(const u16* __restrict__ hbuf,
                                                char* __restrict__ qout,
                                                float* __restrict__ rowdeq){
  const int row = blockIdx.x, tid = threadIdx.x;
  const u16* base = hbuf + (long)row * MLP_P;
  float h[24];
  float amax = 0.f;
#pragma unroll
  for (int it = 0; it < 3; it++){
    int chunk = it*256 + tid;
    if (chunk < 688){
      int j0 = chunk*8;
      int4 h4 = *(const int4*)(base + j0);
      const u16* hp = (const u16*)&h4;
#pragma unroll
      for (int e = 0; e < 8; e++){
        float hv = bf2f(hp[e]);
        h[it*8+e] = hv;
        amax = fmaxf(amax, fabsf(hv));
      }
    } else {
#pragma unroll
      for (int e = 0; e < 8; e++) h[it*8+e] = 0.f;
    }
  }
  amax = waveRedMax(amax);
  __shared__ float sm[4];
  int lane = tid & 63, wv = tid >> 6;
  if (lane == 0) sm[wv] = amax;
  __syncthreads();
  float gmax = fmaxf(fmaxf(sm[0],sm[1]), fmaxf(sm[2],sm[3]));
  float sc = 127.0f / fmaxf(gmax, 1e-5f);
#pragma unroll
  for (int it = 0; it < 3; it++){
    int chunk = it*256 + tid;
    if (chunk < 688){
      int j0 = chunk*8;
      int2 o;
      char* oc = (char*)&o;
#pragma unroll
      for (int e = 0; e < 8; e++)
        oc[e] = (char)(int)fminf(fmaxf(rintf(h[it*8+e]*sc), -128.f), 127.f);
      *(int2*)(qout + (long)row*MLP_P + j0) = o;
    }
  }
  if (tid == 0) rowdeq[row] = 1.0f/sc;
}

extern "C" void kernel_launch(void* const* d_in, const int* in_sizes, int n_in,
                              void* d_out, int out_size, void* d_ws, size_t ws_size,
                              hipStream_t stream)
{
  (void)in_sizes; (void)n_in; (void)out_size; (void)ws_size;
  const float* x   = (const float*)d_in[0];
  const int*   pos = (const int*)d_in[1];
  const float* n1w = (const float*)d_in[2];
  const float* qw  = (const float*)d_in[3];
  const float* qb  = (const float*)d_in[4];
  const float* kw  = (const float*)d_in[5];
  const float* kb  = (const float*)d_in[6];
  const float* vw  = (const float*)d_in[7];
  const float* vb  = (const float*)d_in[8];
  const float* ow  = (const float*)d_in[9];
  const float* n2w = (const float*)d_in[10];
  const float* gw  = (const float*)d_in[11];
  const float* uw  = (const float*)d_in[12];
  const float* dw  = (const float*)d_in[13];
  float* out = (float*)d_out;
  char* ws = (char*)d_ws;

  // workspace layout (all offsets multiple of 256)
  float* sc   = (float*)ws;                 // [0..6] raw abs-sums
  char* Wqkv  = ws + 256;                   // [3072][2048] i8   (6.29 MB)
  char* Wo    = ws + 6291712;               // [2048][2048] i8   (4.19 MB)
  char* Wgu   = ws + 10486016;              // [11008][2048] i8 interleaved (22.5 MB)
  char* Wd    = ws + 33030400;              // [2048][5504] i8   (11.3 MB)
  char* actq  = ws + 44302592;              // [4096][2048] i8   (8.39 MB)
  char* swq   = ws + 52691200;              // [4096][5504] i8   (22.5 MB)
  float* rd   = (float*)(ws + 75235584);    // [4096] fp32
  char* xreg  = ws + 75252224;              // overlay region (90.2 MB)
  u16* yqkv   = (u16*)xreg;                 // [4096][3072] bf16 (25.2 MB)
  u16* attnb  = (u16*)(xreg + 25165824);    // [4096][2048] bf16 (16.8 MB)
  u16* vT     = (u16*)(xreg + 58720256);    // [8][128][2048] bf16 (8.4 MB)
  u16* hbuf   = (u16*)xreg;                 // [4096][5504] bf16 (45.1 MB, after attention)

  // ---- weight scales + ternary i8 quant ----
  hipMemsetAsync(sc, 0, 64, stream);
  k_abssum7<<<dim3(512,7),256,0,stream>>>((const float4*)qw, (const float4*)kw,
                                          (const float4*)vw, (const float4*)ow,
                                          (const float4*)gw, (const float4*)uw,
                                          (const float4*)dw, sc);
  k_wquant6<<<dim3(512,6),256,0,stream>>>((const float4*)qw, (const float4*)kw,
                                          (const float4*)vw, (const float4*)ow,
                                          (const float4*)gw, (const float4*)uw,
                                          (u32*)Wqkv, (u32*)(Wqkv + 2048l*2048),
                                          (u32*)(Wqkv + 2560l*2048), (u32*)Wo,
                                          (u32*)Wgu, sc);
  k_wquant_down<<<11008,256,0,stream>>>(dw, (u32*)Wd, sc+6);

  // ---- attention half ----
  k_rmsq<<<4096,256,0,stream>>>(x, n1w, actq, rd, 1);
  k_gemm2b<128,0><<<768,256,0,stream>>>(actq, Wqkv, 2048, 2048, 2048, 3072, 24, 24,
                                        rd, sc, 0.f, qb, kb, vb, nullptr, nullptr, yqkv);
  k_ropevt2<<<5120,256,0,stream>>>(yqkv, pos, vT);
  k_attn<<<dim3(16,32),256,0,stream>>>(yqkv, vT, attnb);
  k_quantb<<<4096,256,0,stream>>>(attnb, actq, rd);
  k_gemm2b<128,1><<<512,256,0,stream>>>(actq, Wo, 2048, 2048, 2048, 2048, 16, 16,
                                        rd, sc+3, 4194304.f, nullptr, nullptr, nullptr,
                                        x, out, nullptr);

  // ---- MLP half (x1 lives in d_out) ----
  k_rmsq<<<4096,256,0,stream>>>(out, n2w, actq, rd, 1);
  k_gemm2b<256,3><<<1408,256,0,stream>>>(actq, Wgu, 2048, 2048, 2048, MLP_P, 88, 86,
                                         rd, sc+4, 0.f, nullptr, nullptr, nullptr,
                                         nullptr, nullptr, hbuf);
  k_hquant<<<4096,256,0,stream>>>(hbuf, swq, rd);
  k_gemm2b<128,1><<<512,256,0,stream>>>(swq, Wd, 5504, 5504, 5504, 2048, 16, 16,
                                        rd, sc+6, 11184128.f, nullptr, nullptr, nullptr,
                                        out, out, nullptr);
}

// Round 10
// 642.830 us; speedup vs baseline: 1.0788x; 1.0183x over previous
//
#include <hip/hip_runtime.h>

typedef unsigned short u16;
typedef unsigned int   u32;
typedef unsigned char  u8;

using bf16x8 = __attribute__((ext_vector_type(8))) short;
using f32x4  = __attribute__((ext_vector_type(4))) float;
using i32x4  = __attribute__((ext_vector_type(4))) int;

#define SEQ    2048
#define DIMC   2048
#define TOK    4096
#define QKV_N  3072
#define GU_N   11008
#define MLP_P  5504
#define MLP_R  5461
#define ATT_SCALE 0.08838834764831845f

__device__ __forceinline__ float bf2f(u16 v){ return __uint_as_float(((u32)v) << 16); }
__device__ __forceinline__ u16 f2bf(float f){
  u32 x = __float_as_uint(f);
  u32 r = (x + 0x7fffu + ((x >> 16) & 1u)) >> 16;
  return (u16)r;
}

__device__ __forceinline__ float waveRedSum(float v){
#pragma unroll
  for (int o = 32; o > 0; o >>= 1) v += __shfl_xor(v, o);
  return v;
}
__device__ __forceinline__ float waveRedMax(float v){
#pragma unroll
  for (int o = 32; o > 0; o >>= 1) v = fmaxf(v, __shfl_xor(v, o));
  return v;
}

// async global->LDS, 16B per lane. LDS dest is wave-uniform base + lane*16.
#define GLD16(gp, lp) __builtin_amdgcn_global_load_lds( \
    (__attribute__((address_space(1))) void*)(gp), \
    (__attribute__((address_space(3))) void*)(lp), 16, 0, 0)

#define FENCE() asm volatile("" ::: "memory")
#define SBAR()  do{ FENCE(); __builtin_amdgcn_s_barrier(); FENCE(); }while(0)
#define VMCNT(n) asm volatile("s_waitcnt vmcnt(" #n ")" ::: "memory")

// inline dequant scale from raw abs-sum
__device__ __forceinline__ float deq_of(float sum, float cnt){
  return fmaxf(sum/cnt, 1e-5f);
}

// ---------------- fused weight abs-sums (7 regions in one dispatch) ----------------
__global__ __launch_bounds__(256) void k_abssum7(
    const float4* __restrict__ w0, const float4* __restrict__ w1,
    const float4* __restrict__ w2, const float4* __restrict__ w3,
    const float4* __restrict__ w4, const float4* __restrict__ w5,
    const float4* __restrict__ w6, float* __restrict__ sc){
  const int rg = blockIdx.y;
  const float4* w = rg==0?w0: rg==1?w1: rg==2?w2: rg==3?w3: rg==4?w4: rg==5?w5: w6;
  const int n4 = (rg==0||rg==3) ? 1048576 : (rg<4 ? 262144 : 2796032);
  float s = 0.f;
  for (int i = blockIdx.x*256 + threadIdx.x; i < n4; i += gridDim.x*256){
    float4 v = w[i];
    s += fabsf(v.x) + fabsf(v.y) + fabsf(v.z) + fabsf(v.w);
  }
  s = waveRedSum(s);
  __shared__ float sm[4];
  int lane = threadIdx.x & 63, wv = threadIdx.x >> 6;
  if (lane == 0) sm[wv] = s;
  __syncthreads();
  if (threadIdx.x == 0) atomicAdd(sc + rg, sm[0]+sm[1]+sm[2]+sm[3]);
}

// ---------------- fused ternary weight quant (6 regions) -> packed i8 ----------------
// Regions 4 (gate) and 5 (up) are written INTERLEAVED into Wgu:
//   gate row j -> Wgu row 32*(j>>4) + (j&15)
//   up   row j -> Wgu row 32*(j>>4) + 16 + (j&15)
// Gate/up iterate the PADDED row range [0,5504) and write zeros for j >= 5461 —
// bijective onto all 11008 Wgu rows, so no memset dispatch needed.
__global__ __launch_bounds__(256) void k_wquant6(
    const float4* __restrict__ w0, const float4* __restrict__ w1,
    const float4* __restrict__ w2, const float4* __restrict__ w3,
    const float4* __restrict__ w4, const float4* __restrict__ w5,
    u32* __restrict__ d0, u32* __restrict__ d1, u32* __restrict__ d2,
    u32* __restrict__ d3, u32* __restrict__ dgu,
    const float* __restrict__ sc){
  const int rg = blockIdx.y;
  const float4* src = rg==0?w0: rg==1?w1: rg==2?w2: rg==3?w3: rg==4?w4: w5;
  const int n4 = (rg==0||rg==3) ? 1048576 : (rg<4 ? 262144 : 2818048);  // 5504*512 padded
  const float cnt = (rg==0||rg==3) ? 4194304.f : (rg<4 ? 1048576.f : 11184128.f);
  float ws = 1.0f / deq_of(sc[rg], cnt);
  for (int i = blockIdx.x*256 + threadIdx.x; i < n4; i += gridDim.x*256){
    u32 pk = 0;
    int row = i >> 9;
    if (rg < 4 || row < MLP_R){
      float4 v = src[i];
      int c0 = (int)fminf(fmaxf(rintf(v.x*ws), -1.f), 1.f);
      int c1 = (int)fminf(fmaxf(rintf(v.y*ws), -1.f), 1.f);
      int c2 = (int)fminf(fmaxf(rintf(v.z*ws), -1.f), 1.f);
      int c3 = (int)fminf(fmaxf(rintf(v.w*ws), -1.f), 1.f);
      pk = (u32)(u8)c0 | ((u32)(u8)c1 << 8) | ((u32)(u8)c2 << 16) | ((u32)(u8)c3 << 24);
    }
    if (rg < 4){
      u32* dst = rg==0?d0: rg==1?d1: rg==2?d2: d3;
      dst[i] = pk;
    } else {
      int col = i & 511;                          // 512 u32 per 2048-col row
      int rI = 32*(row>>4) + (row&15) + ((rg==5)?16:0);
      dgu[(long)rI*512 + col] = pk;
    }
  }
}

// down_w [2048][5461] fp32 -> [2048][5504] i8 padded with zeros (inline deq from sc[6])
__global__ __launch_bounds__(256) void k_wquant_down(const float* __restrict__ src,
                                                     u32* __restrict__ dst,
                                                     const float* __restrict__ sc6){
  int i = blockIdx.x*256 + threadIdx.x;
  const int total = 2048*(MLP_P/4);
  if (i >= total) return;
  float ws = 1.0f / deq_of(sc6[0], 11184128.f);
  int r = i / (MLP_P/4);
  int c4 = (i - r*(MLP_P/4))*4;
  u32 o = 0;
#pragma unroll
  for (int e = 0; e < 4; e++){
    int c = c4 + e;
    int t = 0;
    if (c < MLP_R) t = (int)fminf(fmaxf(rintf(src[(long)r*MLP_R + c]*ws), -1.f), 1.f);
    o |= (u32)(u8)t << (8*e);
  }
  dst[i] = o;
}

// ---------------- rmsnorm (optional) + act_quant over 2048 fp32 -> i8 ----------------
__global__ __launch_bounds__(256) void k_rmsq(const float* __restrict__ in,
                                              const float* __restrict__ nw,
                                              char* __restrict__ outq,
                                              float* __restrict__ rowdeq, int do_norm){
  const int row = blockIdx.x, tid = threadIdx.x;
  const float* xp = in + (long)row * DIMC + tid*8;
  float v[8];
  float4 a0 = *(const float4*)xp;
  float4 a1 = *(const float4*)(xp + 4);
  v[0]=a0.x; v[1]=a0.y; v[2]=a0.z; v[3]=a0.w;
  v[4]=a1.x; v[5]=a1.y; v[6]=a1.z; v[7]=a1.w;
  float ss = 0.f;
#pragma unroll
  for (int j = 0; j < 8; j++) ss += v[j]*v[j];
  __shared__ float sm[8];
  int lane = tid & 63, wv = tid >> 6;
  ss = waveRedSum(ss);
  if (lane == 0) sm[wv] = ss;
  __syncthreads();
  float h[8];
  float amax = 0.f;
  if (do_norm){
    float tot = sm[0]+sm[1]+sm[2]+sm[3];
    float rms = rsqrtf(tot * (1.0f/DIMC) + 1.1920929e-07f);
    float4 w0 = *(const float4*)(nw + tid*8);
    float4 w1 = *(const float4*)(nw + tid*8 + 4);
    float wr8[8] = {w0.x,w0.y,w0.z,w0.w,w1.x,w1.y,w1.z,w1.w};
#pragma unroll
    for (int j = 0; j < 8; j++){ h[j] = v[j]*rms*wr8[j]; amax = fmaxf(amax, fabsf(h[j])); }
  } else {
#pragma unroll
    for (int j = 0; j < 8; j++){ h[j] = v[j]; amax = fmaxf(amax, fabsf(h[j])); }
  }
  amax = waveRedMax(amax);
  if (lane == 0) sm[4+wv] = amax;
  __syncthreads();
  float gmax = fmaxf(fmaxf(sm[4],sm[5]), fmaxf(sm[6],sm[7]));
  float sc = 127.0f / fmaxf(gmax, 1e-5f);
  int2 o;
  char* oc = (char*)&o;
#pragma unroll
  for (int j = 0; j < 8; j++)
    oc[j] = (char)(int)fminf(fmaxf(rintf(h[j]*sc), -128.f), 127.f);
  *(int2*)(outq + (long)row*DIMC + tid*8) = o;
  if (tid == 0) rowdeq[row] = 1.0f / sc;
}

// ---------------- act_quant over 2048 bf16 -> i8 (attention output) ----------------
__global__ __launch_bounds__(256) void k_quantb(const u16* __restrict__ in,
                                                char* __restrict__ outq,
                                                float* __restrict__ rowdeq){
  const int row = blockIdx.x, tid = threadIdx.x;
  int4 a = *(const int4*)(in + (long)row*DIMC + tid*8);
  const u16* ap = (const u16*)&a;
  float v[8];
  float amax = 0.f;
#pragma unroll
  for (int j = 0; j < 8; j++){ v[j] = bf2f(ap[j]); amax = fmaxf(amax, fabsf(v[j])); }
  amax = waveRedMax(amax);
  __shared__ float sm[4];
  int lane = tid & 63, wv = tid >> 6;
  if (lane == 0) sm[wv] = amax;
  __syncthreads();
  float gmax = fmaxf(fmaxf(sm[0],sm[1]), fmaxf(sm[2],sm[3]));
  float sc = 127.0f / fmaxf(gmax, 1e-5f);
  int2 o;
  char* oc = (char*)&o;
#pragma unroll
  for (int j = 0; j < 8; j++)
    oc[j] = (char)(int)fminf(fmaxf(rintf(v[j]*sc), -128.f), 127.f);
  *(int2*)(outq + (long)row*DIMC + tid*8) = o;
  if (tid == 0) rowdeq[row] = 1.0f / sc;
}

// ---------------- RoPE v2 (per-row LDS sincos table) + V transpose ----------------
__global__ __launch_bounds__(256) void k_ropevt2(u16* __restrict__ y,
                                                 const int* __restrict__ pos_ids,
                                                 u16* __restrict__ VT){
  if (blockIdx.x < 4096){
    const int m = blockIdx.x, tid = threadIdx.x;
    __shared__ float cs[64], sn[64];
    if (tid < 64){
      float pos = (float)pos_ids[m];
      float inv = expf((float)tid * -0.14391156831212787f);  // 10000^(-tid/64)
      float s, c;
      sincosf(pos * inv, &s, &c);
      cs[tid] = c; sn[tid] = s;
    }
    __syncthreads();
    u32* row = (u32*)(y + (long)m*QKV_N);
#pragma unroll
    for (int it = 0; it < 5; it++){
      int p = it*256 + tid;          // pair index < 1280 (cols [0,2560))
      int i = p & 63;
      u32 both = row[p];
      float x0 = bf2f((u16)(both & 0xffffu));
      float x1 = bf2f((u16)(both >> 16));
      float c = cs[i], s = sn[i];
      u16 o0 = f2bf(x0*c - x1*s);
      u16 o1 = f2bf(x1*c + x0*s);
      row[p] = (u32)o0 | ((u32)o1 << 16);
    }
  } else {
    int idx = (int)(blockIdx.x - 4096)*256 + threadIdx.x;  // < 262144
    int d  = idx & 127;
    int hk = (idx >> 7) & 3;
    int b  = (idx >> 9) & 1;
    int tg = idx >> 10;                       // 0..255
    int tok0 = tg*8;
    const u16* src = y + ((long)b*SEQ + tok0)*QKV_N + 2560 + hk*128 + d;
    u16 tmp[8];
#pragma unroll
    for (int e = 0; e < 8; e++) tmp[e] = src[(long)e*QKV_N];
    *(int4*)(VT + (((long)(b*4+hk))*128 + d)*SEQ + tok0) = *(int4*)tmp;
  }
}

// ---------------- GEMM 2b-m: BMx128, 4 waves, MERGED single-phase K-loop -----------
// Same buffers, same staging slots, same vmcnt literals as the R2/R6-proven 2-phase
// version; the two ds_read bursts and two MFMA clusters are merged so each K-tile
// has 2 barriers instead of 4. Hazards preserved:
//   - stA(t+1) -> buf^1 A: its reads retired at previous boundary barrier.
//   - stB(t+2) -> cur B: issued AFTER the mid-tile barrier (all bF reads done).
//   - boundary vmcnt(2): per-wave issue order ... B(t+1)[2], A(t+1)[RA], B(t+2)[2]
//     -> leaves exactly B(t+2) in flight, drains A(t+1)+B(t+1). Same for RA=2,4.
// BM=256 (MODE 3, GU+fused SwiGLU): 48KB LDS -> 2 blocks/CU, XCD-rect mapping.
// BM=128 (MODE 0 QKV / MODE 1 O,Down): 32KB LDS -> 3 blocks/CU, chunked swizzle.
template<int BM, int MODE>
__global__ __launch_bounds__(256, (BM==128)?3:2) void k_gemm2b(
    const char* __restrict__ A, const char* __restrict__ B,
    int K, int lda, int ldb, int ldc, int vnt, int ntreal,
    const float* __restrict__ rowdeq, const float* __restrict__ sums, float cnt,
    const float* __restrict__ bq, const float* __restrict__ bk, const float* __restrict__ bv,
    const float* __restrict__ resid, float* __restrict__ outF,
    u16* __restrict__ outB)
{
  constexpr int BN = 128;
  constexpr int MR = BM/32, NR = 4;              // wave-tile (BM/2)x64
  constexpr int RA = BM/64, RB = 2;              // GLD16 rounds (256 threads)
  constexpr int ASZ = BM*64, BSZ = BN*64;
  constexpr int BUFSZ = ASZ + BSZ;               // 24KB / 16KB
  __shared__ __align__(16) char sm8[2*BUFSZ];

  const int tid = threadIdx.x;
  const int lane = tid & 63, wv = tid >> 6;   // 4 waves
  const int wr = wv >> 1, wc = wv & 1;        // 2x2 wave grid
  const int r = lane & 15, qq = lane >> 4;

  int mt, nt;
  const int lin = blockIdx.x;
  if constexpr (MODE == 3){
    // XCD-rectangle mapping; vnt % 8 == 0, dead virtual blocks exit
    const int xcd = lin & 7, i0 = lin >> 3;
    const int xcdw = vnt >> 3;
    const int ntl = i0 % xcdw; mt = i0 / xcdw;
    nt = xcd*xcdw + ntl;
    if (nt >= ntreal) return;
  } else {
    // chunked bijective XCD swizzle
    const int chunk = gridDim.x >> 3;
    const int swz = (lin & 7)*chunk + (lin >> 3);
    mt = swz / vnt; nt = swz - mt*vnt;
  }
  const long m0 = (long)mt*BM, n0 = (long)nt*BN;

  const char* __restrict__ gA = A + m0*lda;
  const char* __restrict__ gB = B + n0*ldb;

  // staging offsets: LDS linear slot c -> global group g = (c&3)^((row>>1)&3)
  int  soA[RA], soB[RB];
  long goA[RA], goB[RB];
#pragma unroll
  for (int u = 0; u < RA; u++){
    int c = u*256 + tid, row = c >> 2, g = (c & 3) ^ ((row>>1)&3);
    soA[u] = c*16; goA[u] = (long)row*lda + g*16;
  }
#pragma unroll
  for (int u = 0; u < RB; u++){
    int c = u*256 + tid, row = c >> 2, g = (c & 3) ^ ((row>>1)&3);
    soB[u] = c*16; goB[u] = (long)row*ldb + g*16;
  }
  const int gsw = (qq ^ ((r>>1)&3))*16;
  const int aoff0 = (wr*(BM/2) + r)*64 + gsw;
  const int boff0 = (wc*64 + r)*64 + gsw;

  const int NT = K >> 6;

  i32x4 acc[MR][NR];
#pragma unroll
  for (int i = 0; i < MR; i++)
#pragma unroll
    for (int j = 0; j < NR; j++) acc[i][j] = (i32x4){0,0,0,0};

  auto stA = [&](int tq){
    char* dst = sm8 + (tq&1)*BUFSZ;
    const char* src = gA + (long)tq*64;
#pragma unroll
    for (int u = 0; u < RA; u++) GLD16(src + goA[u], dst + soA[u]);
  };
  auto stB = [&](int tq){
    char* dst = sm8 + (tq&1)*BUFSZ + ASZ;
    const char* src = gB + (long)tq*64;
#pragma unroll
    for (int u = 0; u < RB; u++) GLD16(src + goB[u], dst + soB[u]);
  };

  // prologue: A0 B0 B1 in flight; wait A0,B0 landed (B1's RB=2 flying).
  stA(0); stB(0); stB(1);
  VMCNT(2);
  SBAR();

  for (int t = 0; t < NT; t++){
    const char* cA = sm8 + (t&1)*BUFSZ;
    const char* cB = cA + ASZ;
    // merged read burst: all A fragments + all B fragments
    i32x4 aF[MR], bF[NR];
#pragma unroll
    for (int i = 0; i < MR; i++) aF[i] = *(const i32x4*)(cA + aoff0 + i*1024);
#pragma unroll
    for (int j = 0; j < NR; j++) bF[j] = *(const i32x4*)(cB + boff0 + j*1024);
    if (t+1 < NT) stA(t+1);            // into buf^1: its A reads retired last tile
    SBAR();                            // all waves done reading cur A+B
    if (t+2 < NT) stB(t+2);            // into cur B (safe now)
    __builtin_amdgcn_s_setprio(1);
#pragma unroll
    for (int i = 0; i < MR; i++)
#pragma unroll
      for (int j = 0; j < NR; j++)
        acc[i][j] = __builtin_amdgcn_mfma_i32_16x16x64_i8(aF[i], bF[j], acc[i][j], 0,0,0);
    __builtin_amdgcn_s_setprio(0);
    // boundary: t+1 fully landed; B(t+2) (newest 2 reqs) stays in flight.
    if (t + 1 < NT){
      if (t + 2 < NT) VMCNT(2); else VMCNT(0);
    }
    SBAR();
  }

  // epilogue
#pragma unroll
  for (int i = 0; i < MR; i++){
#pragma unroll
    for (int tt = 0; tt < 4; tt++){
      const long row = m0 + wr*(BM/2) + 16*i + 4*qq + tt;
      const float rdv = rowdeq[row];
      if constexpr (MODE == 0){
#pragma unroll
        for (int j = 0; j < NR; j++){
          const long col = n0 + wc*64 + 16*j + r;
          int sec = (col >= 2048) + (col >= 2560);
          float cn = (sec == 0) ? 4194304.f : 1048576.f;
          float dq = deq_of(sums[sec], cn);
          float bias = (sec == 0) ? bq[col] : (sec == 1) ? bk[col-2048] : bv[col-2560];
          float vv = (float)acc[i][j][tt];
          outB[row*(long)ldc + col] = f2bf(vv*rdv*dq + bias);
        }
      } else if constexpr (MODE == 3){
        const float dqg = deq_of(sums[0], 11184128.f);
        const float dqu = deq_of(sums[1], 11184128.f);
#pragma unroll
        for (int j = 0; j < NR; j += 2){
          const long col = n0 + wc*64 + 16*j + r;       // gate col
          float g = (float)acc[i][j][tt]   * rdv * dqg;
          float u = (float)acc[i][j+1][tt] * rdv * dqu;
          float hv = g * (1.0f/(1.0f + __expf(-g))) * u;
          const long hcol = (col >> 5)*16 + (col & 15); // original SwiGLU column
          outB[row*(long)ldc + hcol] = f2bf(hv);
        }
      } else {
        const float deq = deq_of(sums[0], cnt);
#pragma unroll
        for (int j = 0; j < NR; j++){
          const long col = n0 + wc*64 + 16*j + r;
          float vv = (float)acc[i][j][tt];
          outF[row*(long)ldc + col] = vv*rdv*deq + resid[row*(long)ldc + col];
        }
      }
    }
  }
}

// ---------------- flash attention v4: in-place pipelined, swizzled LDS -----------
// Output bf16 (halves O-traffic; consumer quantizes to i8 immediately).
__global__ __launch_bounds__(256) void k_attn(const u16* __restrict__ Y,
                                              const u16* __restrict__ VT,
                                              u16* __restrict__ O)
{
  __shared__ u16 Ks[64*128];     // [key][d], 16B group g stored at g^(key&7)
  __shared__ u16 VTs[128*64];    // [d][key], 16B group g stored at g^(d&7)
  __shared__ u16 Ps[64][72];     // P tile (wave-private rows, padded)

  const int pp = blockIdx.x;               // 0..15
  const int bh = blockIdx.y;
  const int b = bh >> 4, h = bh & 15, hk = h >> 2;
  const int tid = threadIdx.x;
  const int lane = tid & 63, wv = tid >> 6;
  const int r = lane & 15, qq = lane >> 4;
  const long rowbase = (long)b * SEQ;
  const u16* Kbase = Y + rowbase*QKV_N + 2048 + hk*128;
  const u16* Vbase = VT + ((long)(b*4+hk))*128*SEQ;

  for (int ph = 0; ph < 2; ph++){
    const int qt = ph ? pp : 31 - pp;
    const int q0 = qt * 64;

    bf16x8 qf[4];
#pragma unroll
    for (int kc = 0; kc < 4; kc++)
      qf[kc] = *(const bf16x8*)(Y + (rowbase + q0 + wv*16 + r)*QKV_N + h*128 + kc*32 + qq*8);

    // preload tile 0
#pragma unroll
    for (int rnd = 0; rnd < 4; rnd++){
      int c = rnd*256 + tid;
      int row = c >> 4, g = (c & 15) ^ (row & 7);
      GLD16(Kbase + ((long)(qt*0 + row))*QKV_N + g*8, (char*)Ks + c*16);
    }
#pragma unroll
    for (int rnd = 0; rnd < 4; rnd++){
      int c = rnd*256 + tid;
      int d = c >> 3, g = (c & 7) ^ (d & 7);
      GLD16(Vbase + (long)d*SEQ + g*8, (char*)VTs + c*16);
    }
    __syncthreads();

    f32x4 accO[8];
#pragma unroll
    for (int jn = 0; jn < 8; jn++) accO[jn] = (f32x4){0.f,0.f,0.f,0.f};
    float m_run[4] = {-INFINITY,-INFINITY,-INFINITY,-INFINITY};
    float l_run[4] = {0.f,0.f,0.f,0.f};

    for (int kt = 0; kt <= qt; kt++){
      // S = Q K^T
      float sv[4][4];
#pragma unroll
      for (int j = 0; j < 4; j++){
        f32x4 a = (f32x4){0.f,0.f,0.f,0.f};
#pragma unroll
        for (int kc = 0; kc < 4; kc++){
          bf16x8 kf = *(const bf16x8*)(Ks + (16*j + r)*128 + (((kc*4 + qq) ^ (r & 7)))*8);
          a = __builtin_amdgcn_mfma_f32_16x16x32_bf16(qf[kc], kf, a, 0, 0, 0);
        }
#pragma unroll
        for (int t = 0; t < 4; t++) sv[j][t] = a[t] * ATT_SCALE;
      }
      __syncthreads();                       // bar1: Ks free; drains V(kt) of prev iter
      if (kt < qt){
#pragma unroll
        for (int rnd = 0; rnd < 4; rnd++){
          int c = rnd*256 + tid;
          int row = c >> 4, g = (c & 15) ^ (row & 7);
          GLD16(Kbase + ((long)((kt+1)*64 + row))*QKV_N + g*8, (char*)Ks + c*16);
        }
      }
      if (kt == qt){
#pragma unroll
        for (int j = 0; j < 4; j++){
          int key = kt*64 + 16*j + r;
#pragma unroll
          for (int t = 0; t < 4; t++){
            int qr = q0 + wv*16 + 4*qq + t;
            if (key > qr) sv[j][t] = -INFINITY;
          }
        }
      }
      // online softmax per q-row
#pragma unroll
      for (int t = 0; t < 4; t++){
        float mm = fmaxf(fmaxf(sv[0][t],sv[1][t]), fmaxf(sv[2][t],sv[3][t]));
#pragma unroll
        for (int o = 8; o > 0; o >>= 1) mm = fmaxf(mm, __shfl_xor(mm, o));
        float mnew = fmaxf(m_run[t], mm);
        float alpha = __expf(m_run[t] - mnew);
        m_run[t] = mnew;
        float ps = 0.f;
#pragma unroll
        for (int j = 0; j < 4; j++){
          float p = __expf(sv[j][t] - mnew);
          ps += p;
          Ps[wv*16 + 4*qq + t][16*j + r] = f2bf(p);
        }
#pragma unroll
        for (int o = 8; o > 0; o >>= 1) ps += __shfl_xor(ps, o);
        l_run[t] = l_run[t]*alpha + ps;
#pragma unroll
        for (int jn = 0; jn < 8; jn++) accO[jn][t] *= alpha;
      }
      // O += P V
#pragma unroll
      for (int kc = 0; kc < 2; kc++){
        bf16x8 pf = *(const bf16x8*)&Ps[wv*16 + r][kc*32 + qq*8];
#pragma unroll
        for (int jn = 0; jn < 8; jn++){
          bf16x8 vf = *(const bf16x8*)(VTs + (16*jn + r)*64 + (((kc*4 + qq) ^ (r & 7)))*8);
          accO[jn] = __builtin_amdgcn_mfma_f32_16x16x32_bf16(pf, vf, accO[jn], 0, 0, 0);
        }
      }
      __syncthreads();                       // bar2: VTs free; drains K(kt+1)
      if (kt < qt){
#pragma unroll
        for (int rnd = 0; rnd < 4; rnd++){
          int c = rnd*256 + tid;
          int d = c >> 3, g = (c & 7) ^ (d & 7);
          GLD16(Vbase + (long)d*SEQ + (kt+1)*64 + g*8, (char*)VTs + c*16);
        }
      }
    }
    float inv[4];
#pragma unroll
    for (int t = 0; t < 4; t++) inv[t] = 1.0f / l_run[t];
#pragma unroll
    for (int jn = 0; jn < 8; jn++){
#pragma unroll
      for (int t = 0; t < 4; t++){
        long row = rowbase + q0 + wv*16 + 4*qq + t;
        O[row*DIMC + h*128 + 16*jn + r] = f2bf(accO[jn][t]*inv[t]);
      }
    }
    __syncthreads();   // protect Ks/VTs before next phase preload
  }
}

// ---------------- h bf16 [4096][5504] -> act_quant i8 ----------------
__global__ __launch_bounds__(256) void k_hquant(const u16* __restrict__ hbuf,
                                                char* __restrict__ qout,
                                                float* __restrict__ rowdeq){
  const int row = blockIdx.x, tid = threadIdx.x;
  const u16* base = hbuf + (long)row * MLP_P;
  float h[24];
  float amax = 0.f;
#pragma unroll
  for (int it = 0; it < 3; it++){
    int chunk = it*256 + tid;
    if (chunk < 688){
      int j0 = chunk*8;
      int4 h4 = *(const int4*)(base + j0);
      const u16* hp = (const u16*)&h4;
#pragma unroll
      for (int e = 0; e < 8; e++){
        float hv = bf2f(hp[e]);
        h[it*8+e] = hv;
        amax = fmaxf(amax, fabsf(hv));
      }
    } else {
#pragma unroll
      for (int e = 0; e < 8; e++) h[it*8+e] = 0.f;
    }
  }
  amax = waveRedMax(amax);
  __shared__ float sm[4];
  int lane = tid & 63, wv = tid >> 6;
  if (lane == 0) sm[wv] = amax;
  __syncthreads();
  float gmax = fmaxf(fmaxf(sm[0],sm[1]), fmaxf(sm[2],sm[3]));
  float sc = 127.0f / fmaxf(gmax, 1e-5f);
#pragma unroll
  for (int it = 0; it < 3; it++){
    int chunk = it*256 + tid;
    if (chunk < 688){
      int j0 = chunk*8;
      int2 o;
      char* oc = (char*)&o;
#pragma unroll
      for (int e = 0; e < 8; e++)
        oc[e] = (char)(int)fminf(fmaxf(rintf(h[it*8+e]*sc), -128.f), 127.f);
      *(int2*)(qout + (long)row*MLP_P + j0) = o;
    }
  }
  if (tid == 0) rowdeq[row] = 1.0f/sc;
}

extern "C" void kernel_launch(void* const* d_in, const int* in_sizes, int n_in,
                              void* d_out, int out_size, void* d_ws, size_t ws_size,
                              hipStream_t stream)
{
  (void)in_sizes; (void)n_in; (void)out_size; (void)ws_size;
  const float* x   = (const float*)d_in[0];
  const int*   pos = (const int*)d_in[1];
  const float* n1w = (const float*)d_in[2];
  const float* qw  = (const float*)d_in[3];
  const float* qb  = (const float*)d_in[4];
  const float* kw  = (const float*)d_in[5];
  const float* kb  = (const float*)d_in[6];
  const float* vw  = (const float*)d_in[7];
  const float* vb  = (const float*)d_in[8];
  const float* ow  = (const float*)d_in[9];
  const float* n2w = (const float*)d_in[10];
  const float* gw  = (const float*)d_in[11];
  const float* uw  = (const float*)d_in[12];
  const float* dw  = (const float*)d_in[13];
  float* out = (float*)d_out;
  char* ws = (char*)d_ws;

  // workspace layout (all offsets multiple of 256)
  float* sc   = (float*)ws;                 // [0..6] raw abs-sums
  char* Wqkv  = ws + 256;                   // [3072][2048] i8   (6.29 MB)
  char* Wo    = ws + 6291712;               // [2048][2048] i8   (4.19 MB)
  char* Wgu   = ws + 10486016;              // [11008][2048] i8 interleaved (22.5 MB)
  char* Wd    = ws + 33030400;              // [2048][5504] i8   (11.3 MB)
  char* actq  = ws + 44302592;              // [4096][2048] i8   (8.39 MB)
  char* swq   = ws + 52691200;              // [4096][5504] i8   (22.5 MB)
  float* rd   = (float*)(ws + 75235584);    // [4096] fp32
  char* xreg  = ws + 75252224;              // overlay region (90.2 MB)
  u16* yqkv   = (u16*)xreg;                 // [4096][3072] bf16 (25.2 MB)
  u16* attnb  = (u16*)(xreg + 25165824);    // [4096][2048] bf16 (16.8 MB)
  u16* vT     = (u16*)(xreg + 58720256);    // [8][128][2048] bf16 (8.4 MB)
  u16* hbuf   = (u16*)xreg;                 // [4096][5504] bf16 (45.1 MB, after attention)

  // ---- weight scales + ternary i8 quant ----
  hipMemsetAsync(sc, 0, 64, stream);
  k_abssum7<<<dim3(512,7),256,0,stream>>>((const float4*)qw, (const float4*)kw,
                                          (const float4*)vw, (const float4*)ow,
                                          (const float4*)gw, (const float4*)uw,
                                          (const float4*)dw, sc);
  k_wquant6<<<dim3(512,6),256,0,stream>>>((const float4*)qw, (const float4*)kw,
                                          (const float4*)vw, (const float4*)ow,
                                          (const float4*)gw, (const float4*)uw,
                                          (u32*)Wqkv, (u32*)(Wqkv + 2048l*2048),
                                          (u32*)(Wqkv + 2560l*2048), (u32*)Wo,
                                          (u32*)Wgu, sc);
  k_wquant_down<<<11008,256,0,stream>>>(dw, (u32*)Wd, sc+6);

  // ---- attention half ----
  k_rmsq<<<4096,256,0,stream>>>(x, n1w, actq, rd, 1);
  k_gemm2b<128,0><<<768,256,0,stream>>>(actq, Wqkv, 2048, 2048, 2048, 3072, 24, 24,
                                        rd, sc, 0.f, qb, kb, vb, nullptr, nullptr, yqkv);
  k_ropevt2<<<5120,256,0,stream>>>(yqkv, pos, vT);
  k_attn<<<dim3(16,32),256,0,stream>>>(yqkv, vT, attnb);
  k_quantb<<<4096,256,0,stream>>>(attnb, actq, rd);
  k_gemm2b<128,1><<<512,256,0,stream>>>(actq, Wo, 2048, 2048, 2048, 2048, 16, 16,
                                        rd, sc+3, 4194304.f, nullptr, nullptr, nullptr,
                                        x, out, nullptr);

  // ---- MLP half (x1 lives in d_out) ----
  k_rmsq<<<4096,256,0,stream>>>(out, n2w, actq, rd, 1);
  k_gemm2b<256,3><<<1408,256,0,stream>>>(actq, Wgu, 2048, 2048, 2048, MLP_P, 88, 86,
                                         rd, sc+4, 0.f, nullptr, nullptr, nullptr,
                                         nullptr, nullptr, hbuf);
  k_hquant<<<4096,256,0,stream>>>(hbuf, swq, rd);
  k_gemm2b<128,1><<<512,256,0,stream>>>(swq, Wd, 5504, 5504, 5504, 2048, 16, 16,
                                        rd, sc+6, 11184128.f, nullptr, nullptr, nullptr,
                                        out, out, nullptr);
}